// Round 21
// baseline (233.443 us; speedup 1.0000x reference)
//
#include <hip/hip_runtime.h>
#include <hip/hip_bf16.h>

#define H_    2048
#define NH_   16
#define KD_   1024
#define DK_   64
#define T_    1024
#define B_    2
#define M_    (B_*T_)     // 2048 rows
#define RL_   64
#define CC_   32          // scan chunk length
#define NC_   (T_/CC_)    // 32 chunks per sequence

typedef short bf16x8 __attribute__((ext_vector_type(8)));   // 8 bf16 (4 VGPR)
typedef float f32x4  __attribute__((ext_vector_type(4)));   // MFMA acc

__device__ __forceinline__ ushort bf16r(float f) {          // RNE fp32->bf16
    union { float f; unsigned u; } v; v.f = f;
    return (ushort)((v.u + 0x7FFF + ((v.u >> 16) & 1)) >> 16);
}

// async global->LDS, 16B per lane; lds base must be wave-uniform
__device__ __forceinline__ void gl_lds16(const void* g, void* l) {
    __builtin_amdgcn_global_load_lds((const __attribute__((address_space(1))) void*)g,
                                     (__attribute__((address_space(3))) void*)l, 16, 0, 0);
}

// XCD-aware bijective block swizzle (requires nwg % 8 == 0)
__device__ __forceinline__ void xcd_swz(int& bx, int& by, int& bz) {
    int gx = gridDim.x, gy = gridDim.y;
    int nwg = gx * gy * gridDim.z;
    int bid = ((int)blockIdx.z * gy + blockIdx.y) * gx + blockIdx.x;
    int swz = (bid & 7) * (nwg >> 3) + (bid >> 3);
    bx = swz % gx;
    int rem = swz / gx;
    by = rem % gy;
    bz = rem / gy;
}

// ---------------------------------------------------------------------------
// Tiled bf16 layouts:
//  A-tiles (BM=128, BK=32): 4096 bf16/tile, elem (r,k): off = (g*128+r)*8+(k&7), g=(k>>3)&3
//  B-tiles (BN=64, BK=32): 2048 bf16/tile, elem (c,k): off = (g*64+c)*8+(k&7)
// ---------------------------------------------------------------------------

// xx = x + (shift(x)-x)*mu_x  -> tiled bf16 A-layout (chunk per thread)
__global__ __launch_bounds__(256) void mix_mu_t(const float* __restrict__ x,
                                                const float* __restrict__ mu,
                                                ushort* __restrict__ At) {
    int c = blockIdx.x * 256 + threadIdx.x;       // chunk id 0..M_*H_/8
    int bt = c >> 8, k8 = c & 255;
    int k = k8 << 3;
    int t = bt & (T_ - 1);
    const float* xp = &x[(size_t)bt * H_ + k];
    float4 xa = *(const float4*)xp;
    float4 xb = *(const float4*)(xp + 4);
    float4 sa = make_float4(0,0,0,0), sb = make_float4(0,0,0,0);
    if (t > 0) { sa = *(const float4*)(xp - H_); sb = *(const float4*)(xp - H_ + 4); }
    float4 ma = *(const float4*)&mu[k];
    float4 mb = *(const float4*)&mu[k + 4];
    ushort o[8];
    o[0] = bf16r(xa.x + (sa.x - xa.x) * ma.x);
    o[1] = bf16r(xa.y + (sa.y - xa.y) * ma.y);
    o[2] = bf16r(xa.z + (sa.z - xa.z) * ma.z);
    o[3] = bf16r(xa.w + (sa.w - xa.w) * ma.w);
    o[4] = bf16r(xb.x + (sb.x - xb.x) * mb.x);
    o[5] = bf16r(xb.y + (sb.y - xb.y) * mb.y);
    o[6] = bf16r(xb.z + (sb.z - xb.z) * mb.z);
    o[7] = bf16r(xb.w + (sb.w - xb.w) * mb.w);
    int rb = bt >> 7, kb = k8 >> 2, g = k8 & 3, r = bt & 127;
    *(uint4*)&At[(((size_t)(rb * 64 + kb)) << 12) + ((g << 7) + r) * 8] = *(uint4*)o;
}

// ---------------------------------------------------------------------------
// W [K][N] fp32 -> tiled bf16 B-layout (per 32x64 tile block, LDS transpose)
__global__ __launch_bounds__(256) void convert_w(const float* __restrict__ W,
                                                 ushort* __restrict__ Wt,
                                                 int K, int N) {
    __shared__ float s[32][68];
    int kb = blockIdx.y, nb = blockIdx.x;
    int t = threadIdx.x;
    #pragma unroll
    for (int i = 0; i < 2; ++i) {
        int q = t + i * 256;
        int k = q >> 4, c4 = (q & 15) << 2;
        *(float4*)&s[k][c4] = *(const float4*)&W[(size_t)(kb * 32 + k) * N + nb * 64 + c4];
    }
    __syncthreads();
    int g = t >> 6, c = t & 63;
    ushort o[8];
    #pragma unroll
    for (int e = 0; e < 8; ++e) o[e] = bf16r(s[g * 8 + e][c]);
    *(uint4*)&Wt[((size_t)(nb * (K >> 5) + kb)) * 2048 + t * 8] = *(uint4*)o;
}

// r/k/v weights in one dispatch (z selects)
__global__ __launch_bounds__(256) void convert_w3(const float* __restrict__ W0,
                                                  const float* __restrict__ W1,
                                                  const float* __restrict__ W2,
                                                  ushort* __restrict__ Wt) {
    __shared__ float s[32][68];
    int z = blockIdx.z;
    const float* W = (z == 0) ? W0 : (z == 1) ? W1 : W2;
    ushort* dst = Wt + (size_t)z * ((size_t)H_ * KD_);
    int kb = blockIdx.y, nb = blockIdx.x;
    int t = threadIdx.x;
    #pragma unroll
    for (int i = 0; i < 2; ++i) {
        int q = t + i * 256;
        int k = q >> 4, c4 = (q & 15) << 2;
        *(float4*)&s[k][c4] = *(const float4*)&W[(size_t)(kb * 32 + k) * KD_ + nb * 64 + c4];
    }
    __syncthreads();
    int g = t >> 6, c = t & 63;
    ushort o[8];
    #pragma unroll
    for (int e = 0; e < 8; ++e) o[e] = bf16r(s[g * 8 + e][c]);
    *(uint4*)&dst[((size_t)(nb * (H_ >> 5) + kb)) * 2048 + t * 8] = *(uint4*)o;
}

// Wx2 [H][5*64] fp32 -> per-branch B-tiled bf16: tile ((z*32+nb)*2+kb), K=64
__global__ __launch_bounds__(256) void convert_wx2(const float* __restrict__ Wx2,
                                                   ushort* __restrict__ Wt) {
    __shared__ float s[64][68];
    int nb = blockIdx.x, z = blockIdx.y;
    int t = threadIdx.x;
    for (int q = t; q < 1024; q += 256) {
        int row = q >> 4, c4 = (q & 15) << 2;
        *(float4*)&s[row][c4] = *(const float4*)&Wx2[(size_t)(nb * 64 + row) * 320 + z * 64 + c4];
    }
    __syncthreads();
    for (int q = t; q < 512; q += 256) {
        int kb = q >> 8, i = q & 255;
        int g = i >> 6, c = i & 63;
        ushort o[8];
        #pragma unroll
        for (int e = 0; e < 8; ++e) o[e] = bf16r(s[c][kb * 32 + g * 8 + e]);
        *(uint4*)&Wt[(((size_t)(z * 32 + nb)) * 2 + kb) * 2048 + i * 8] = *(uint4*)o;
    }
}

// ---------------------------------------------------------------------------
// bf16 MFMA GEMM, BM=128 x BN=64, BK=64 (two 32-K subtiles per iteration).
// Double-buffered global_load_lds staging, XCD-swizzled grid.
// NB>1: z selects branch. EPI: 0 = none, 1 = tanh
template<int EPI, int NB>
__global__ __launch_bounds__(256) void gemm_bf16t(const ushort* __restrict__ A0,
                                                  const ushort* __restrict__ A1,
                                                  const ushort* __restrict__ A2,
                                                  const ushort* __restrict__ Bt0,
                                                  float* __restrict__ C0,
                                                  int K, int ldc) {
    __shared__ ushort Alds[2][8192];
    __shared__ ushort Blds[2][4096];
    int bx, by, bz;
    xcd_swz(bx, by, bz);
    int tid = threadIdx.x;
    int w = tid >> 6, l = tid & 63;
    int KB32 = K >> 5;           // 32-K tiles (addressing)
    int KB64 = K >> 6;           // loop iterations
    int z = (NB > 1) ? bz : 0;
    const ushort* At = (NB > 1) ? (z == 0 ? A0 : z == 1 ? A1 : A2) : A0;
    const ushort* Bt = Bt0 + (size_t)z * ((size_t)H_ * KD_);
    float* C = C0 + (size_t)z * ((size_t)M_ * KD_);
    const ushort* Ag = At + (size_t)by * KB32 * 4096 + tid * 8;
    const ushort* Bg = Bt + (size_t)bx * KB32 * 2048 + tid * 8;
    int wr = (w >> 1) << 6, wc = (w & 1) << 5;
    int a_off = (((l >> 4) << 7) + wr + (l & 15)) << 3;
    int b_off = (((l >> 4) << 6) + wc + (l & 15)) << 3;
    f32x4 acc[8] = {};
    #pragma unroll
    for (int j = 0; j < 4; ++j) gl_lds16(Ag + j * 2048, &Alds[0][w * 512 + j * 2048]);
    #pragma unroll
    for (int j = 0; j < 2; ++j) gl_lds16(Bg + j * 2048, &Blds[0][w * 512 + j * 2048]);
    __syncthreads();
    for (int kt = 0; kt < KB64; ++kt) {
        int cur = kt & 1;
        if (kt + 1 < KB64) {
            Ag += 8192; Bg += 4096;
            int nxt = cur ^ 1;
            #pragma unroll
            for (int j = 0; j < 4; ++j) gl_lds16(Ag + j * 2048, &Alds[nxt][w * 512 + j * 2048]);
            #pragma unroll
            for (int j = 0; j < 2; ++j) gl_lds16(Bg + j * 2048, &Blds[nxt][w * 512 + j * 2048]);
        }
        #pragma unroll
        for (int kb2 = 0; kb2 < 2; ++kb2) {
            const ushort* Ab = &Alds[cur][kb2 * 4096 + a_off];
            const ushort* Bb = &Blds[cur][kb2 * 2048 + b_off];
            bf16x8 af0 = *(const bf16x8*)(Ab);
            bf16x8 af1 = *(const bf16x8*)(Ab + 128);
            bf16x8 af2 = *(const bf16x8*)(Ab + 256);
            bf16x8 af3 = *(const bf16x8*)(Ab + 384);
            bf16x8 bf0 = *(const bf16x8*)(Bb);
            bf16x8 bf1 = *(const bf16x8*)(Bb + 128);
            acc[0] = __builtin_amdgcn_mfma_f32_16x16x32_bf16(af0, bf0, acc[0], 0, 0, 0);
            acc[1] = __builtin_amdgcn_mfma_f32_16x16x32_bf16(af0, bf1, acc[1], 0, 0, 0);
            acc[2] = __builtin_amdgcn_mfma_f32_16x16x32_bf16(af1, bf0, acc[2], 0, 0, 0);
            acc[3] = __builtin_amdgcn_mfma_f32_16x16x32_bf16(af1, bf1, acc[3], 0, 0, 0);
            acc[4] = __builtin_amdgcn_mfma_f32_16x16x32_bf16(af2, bf0, acc[4], 0, 0, 0);
            acc[5] = __builtin_amdgcn_mfma_f32_16x16x32_bf16(af2, bf1, acc[5], 0, 0, 0);
            acc[6] = __builtin_amdgcn_mfma_f32_16x16x32_bf16(af3, bf0, acc[6], 0, 0, 0);
            acc[7] = __builtin_amdgcn_mfma_f32_16x16x32_bf16(af3, bf1, acc[7], 0, 0, 0);
        }
        __syncthreads();
    }
    int row0 = (by << 7) + wr + ((l >> 4) << 2);
    int col0 = (bx << 6) + wc + (l & 15);
    #pragma unroll
    for (int fr = 0; fr < 4; ++fr)
        #pragma unroll
        for (int fc = 0; fc < 2; ++fc) {
            f32x4 v = acc[fr * 2 + fc];
            #pragma unroll
            for (int q = 0; q < 4; ++q) {
                float o = v[q];
                if (EPI == 1) o = tanhf(o);
                C[(size_t)(row0 + fr * 16 + q) * ldc + col0 + fc * 16] = o;
            }
        }
}

// ---------------------------------------------------------------------------
// Wx1 GEMM variant: K=2048, BK=64, grid (branch=5, rb=16), XCD-swizzled;
// epilogue writes lr = tanh(acc) as bf16 A-fragment-tiled lrt (K=64/branch).
__global__ __launch_bounds__(256) void gemm_bf16t_lr(const ushort* __restrict__ At,
                                                     const ushort* __restrict__ Bt,
                                                     ushort* __restrict__ lrt) {
    __shared__ ushort Alds[2][8192];
    __shared__ ushort Blds[2][4096];
    int bx, by, bz;
    xcd_swz(bx, by, bz);
    int tid = threadIdx.x;
    int w = tid >> 6, l = tid & 63;
    const int KB32 = H_ >> 5;   // 64 tiles
    const int KB64 = H_ >> 6;   // 32 iterations
    const ushort* Ag = At + (size_t)by * KB32 * 4096 + tid * 8;
    const ushort* Bg = Bt + (size_t)bx * KB32 * 2048 + tid * 8;
    int wr = (w >> 1) << 6, wc = (w & 1) << 5;
    int a_off = (((l >> 4) << 7) + wr + (l & 15)) << 3;
    int b_off = (((l >> 4) << 6) + wc + (l & 15)) << 3;
    f32x4 acc[8] = {};
    #pragma unroll
    for (int j = 0; j < 4; ++j) gl_lds16(Ag + j * 2048, &Alds[0][w * 512 + j * 2048]);
    #pragma unroll
    for (int j = 0; j < 2; ++j) gl_lds16(Bg + j * 2048, &Blds[0][w * 512 + j * 2048]);
    __syncthreads();
    for (int kt = 0; kt < KB64; ++kt) {
        int cur = kt & 1;
        if (kt + 1 < KB64) {
            Ag += 8192; Bg += 4096;
            int nxt = cur ^ 1;
            #pragma unroll
            for (int j = 0; j < 4; ++j) gl_lds16(Ag + j * 2048, &Alds[nxt][w * 512 + j * 2048]);
            #pragma unroll
            for (int j = 0; j < 2; ++j) gl_lds16(Bg + j * 2048, &Blds[nxt][w * 512 + j * 2048]);
        }
        #pragma unroll
        for (int kb2 = 0; kb2 < 2; ++kb2) {
            const ushort* Ab = &Alds[cur][kb2 * 4096 + a_off];
            const ushort* Bb = &Blds[cur][kb2 * 2048 + b_off];
            bf16x8 af0 = *(const bf16x8*)(Ab);
            bf16x8 af1 = *(const bf16x8*)(Ab + 128);
            bf16x8 af2 = *(const bf16x8*)(Ab + 256);
            bf16x8 af3 = *(const bf16x8*)(Ab + 384);
            bf16x8 bf0 = *(const bf16x8*)(Bb);
            bf16x8 bf1 = *(const bf16x8*)(Bb + 128);
            acc[0] = __builtin_amdgcn_mfma_f32_16x16x32_bf16(af0, bf0, acc[0], 0, 0, 0);
            acc[1] = __builtin_amdgcn_mfma_f32_16x16x32_bf16(af0, bf1, acc[1], 0, 0, 0);
            acc[2] = __builtin_amdgcn_mfma_f32_16x16x32_bf16(af1, bf0, acc[2], 0, 0, 0);
            acc[3] = __builtin_amdgcn_mfma_f32_16x16x32_bf16(af1, bf1, acc[3], 0, 0, 0);
            acc[4] = __builtin_amdgcn_mfma_f32_16x16x32_bf16(af2, bf0, acc[4], 0, 0, 0);
            acc[5] = __builtin_amdgcn_mfma_f32_16x16x32_bf16(af2, bf1, acc[5], 0, 0, 0);
            acc[6] = __builtin_amdgcn_mfma_f32_16x16x32_bf16(af3, bf0, acc[6], 0, 0, 0);
            acc[7] = __builtin_amdgcn_mfma_f32_16x16x32_bf16(af3, bf1, acc[7], 0, 0, 0);
        }
        __syncthreads();
    }
    int rloc0 = wr + ((l >> 4) << 2);              // local row in [0,128)
    size_t tbase = ((size_t)(by * 5 + bx)) * 8192;
    #pragma unroll
    for (int fr = 0; fr < 4; ++fr)
        #pragma unroll
        for (int fc = 0; fc < 2; ++fc) {
            f32x4 v = acc[fr * 2 + fc];
            int c = wc + fc * 16 + (l & 15);       // branch-local K index [0,64)
            int kb2 = c >> 5, g = (c >> 3) & 3, e = c & 7;
            #pragma unroll
            for (int q = 0; q < 4; ++q) {
                int r = rloc0 + fr * 16 + q;
                lrt[tbase + (size_t)kb2 * 4096 + ((g << 7) + r) * 8 + e] = bf16r(tanhf(v[q]));
            }
        }
}

// ---------------------------------------------------------------------------
// MFMA mus-GEMM + lerp: C = lrt @ Wx2t (K=64) per branch z; epilogue applies
// bias + lerp vs x/shift and writes branch-specific outputs.
__global__ __launch_bounds__(256) void musgemm_mfma(const ushort* __restrict__ lrt,
                                                    const ushort* __restrict__ wx2t,
                                                    const float* __restrict__ x,
                                                    const float* __restrict__ xbias,
                                                    ushort* __restrict__ xmt_r,
                                                    float*  __restrict__ xm_w,
                                                    ushort* __restrict__ xmt_k,
                                                    ushort* __restrict__ xmt_v,
                                                    float*  __restrict__ xm_g) {
    __shared__ ushort Alds[8192];
    __shared__ ushort Blds[4096];
    int tid = threadIdx.x;
    int w = tid >> 6, l = tid & 63;
    int z = blockIdx.z;
    const ushort* Ag = lrt + ((size_t)(blockIdx.y * 5 + z)) * 8192 + tid * 8;
    const ushort* Bg = wx2t + ((size_t)(z * 32 + blockIdx.x)) * 4096 + tid * 8;
    gl_lds16(Ag,        &Alds[w * 512]);
    gl_lds16(Ag + 2048, &Alds[w * 512 + 2048]);
    gl_lds16(Ag + 4096, &Alds[w * 512 + 4096]);
    gl_lds16(Ag + 6144, &Alds[w * 512 + 6144]);
    gl_lds16(Bg,        &Blds[w * 512]);
    gl_lds16(Bg + 2048, &Blds[w * 512 + 2048]);
    int wr = (w >> 1) << 6, wc = (w & 1) << 5;
    int a_off = (((l >> 4) << 7) + wr + (l & 15)) << 3;
    int b_off = (((l >> 4) << 6) + wc + (l & 15)) << 3;
    f32x4 acc[8] = {};
    __syncthreads();
    #pragma unroll
    for (int kb = 0; kb < 2; ++kb) {
        const ushort* Ab = &Alds[kb * 4096 + a_off];
        const ushort* Bb = &Blds[kb * 2048 + b_off];
        bf16x8 af0 = *(const bf16x8*)(Ab);
        bf16x8 af1 = *(const bf16x8*)(Ab + 128);
        bf16x8 af2 = *(const bf16x8*)(Ab + 256);
        bf16x8 af3 = *(const bf16x8*)(Ab + 384);
        bf16x8 bf0 = *(const bf16x8*)(Bb);
        bf16x8 bf1 = *(const bf16x8*)(Bb + 128);
        acc[0] = __builtin_amdgcn_mfma_f32_16x16x32_bf16(af0, bf0, acc[0], 0, 0, 0);
        acc[1] = __builtin_amdgcn_mfma_f32_16x16x32_bf16(af0, bf1, acc[1], 0, 0, 0);
        acc[2] = __builtin_amdgcn_mfma_f32_16x16x32_bf16(af1, bf0, acc[2], 0, 0, 0);
        acc[3] = __builtin_amdgcn_mfma_f32_16x16x32_bf16(af1, bf1, acc[3], 0, 0, 0);
        acc[4] = __builtin_amdgcn_mfma_f32_16x16x32_bf16(af2, bf0, acc[4], 0, 0, 0);
        acc[5] = __builtin_amdgcn_mfma_f32_16x16x32_bf16(af2, bf1, acc[5], 0, 0, 0);
        acc[6] = __builtin_amdgcn_mfma_f32_16x16x32_bf16(af3, bf0, acc[6], 0, 0, 0);
        acc[7] = __builtin_amdgcn_mfma_f32_16x16x32_bf16(af3, bf1, acc[7], 0, 0, 0);
    }
    int row0 = (blockIdx.y << 7) + wr + ((l >> 4) << 2);
    int col0 = (blockIdx.x << 6) + wc + (l & 15);
    #pragma unroll
    for (int fr = 0; fr < 4; ++fr)
        #pragma unroll
        for (int fc = 0; fc < 2; ++fc) {
            f32x4 v = acc[fr * 2 + fc];
            int h = col0 + fc * 16;
            float bias = xbias[z * H_ + h];
            #pragma unroll
            for (int q = 0; q < 4; ++q) {
                int r = row0 + fr * 16 + q;
                int t = r & (T_ - 1);
                const float* xp = &x[(size_t)r * H_ + h];
                float xv = *xp;
                float sh = (t > 0) ? *(xp - H_) : 0.f;
                float o = xv + (sh - xv) * (v[q] + bias);
                if (z == 0 || z == 2 || z == 3) {
                    ushort* dst = (z == 0) ? xmt_r : (z == 2) ? xmt_k : xmt_v;
                    int rb = r >> 7, kb = h >> 5, g = (h >> 3) & 3;
                    dst[(((size_t)(rb * 64 + kb)) << 12) + ((g << 7) + (r & 127)) * 8 + (h & 7)] = bf16r(o);
                } else {
                    float* dst = (z == 1) ? xm_w : xm_g;
                    dst[(size_t)r * H_ + h] = o;
                }
            }
        }
}

// ---------------------------------------------------------------------------
// Fused LoRA up-projections (z=0: decay path, z=1: gate path), K=64.
__global__ __launch_bounds__(256) void gemm_f32_up2(const float* __restrict__ hidw,
                                                    const float* __restrict__ hidg,
                                                    const float* __restrict__ Wwb,
                                                    const float* __restrict__ Wgb,
                                                    const float* __restrict__ bw,
                                                    const float* __restrict__ bg,
                                                    float* __restrict__ db,
                                                    float* __restrict__ gb) {
    __shared__ float As[16][68];
    __shared__ float Bs[16][68];
    int z = blockIdx.z;
    const float* A = z ? hidg : hidw;
    const float* W = z ? Wgb : Wwb;
    const float* bias = z ? bg : bw;
    float* C = z ? gb : db;
    int tid = threadIdx.x;
    int tx = tid & 15, ty = tid >> 4;
    int row0 = blockIdx.y * 64, col0 = blockIdx.x * 64;
    int am = tid >> 2, ak = (tid & 3) << 2;
    int bk = tid >> 4, bn = (tid & 15) << 2;
    float acc[4][4] = {};
    float4 av = *(const float4*)&A[(size_t)(row0 + am) * 64 + ak];
    float4 bv = *(const float4*)&W[(size_t)bk * KD_ + col0 + bn];
    for (int k0 = 0; k0 < 64; k0 += 16) {
        __syncthreads();
        As[ak + 0][am] = av.x; As[ak + 1][am] = av.y;
        As[ak + 2][am] = av.z; As[ak + 3][am] = av.w;
        *(float4*)&Bs[bk][bn] = bv;
        __syncthreads();
        if (k0 + 16 < 64) {
            av = *(const float4*)&A[(size_t)(row0 + am) * 64 + k0 + 16 + ak];
            bv = *(const float4*)&W[(size_t)(k0 + 16 + bk) * KD_ + col0 + bn];
        }
        #pragma unroll
        for (int kk = 0; kk < 16; ++kk) {
            float4 a = *(const float4*)&As[kk][ty << 2];
            float4 b = *(const float4*)&Bs[kk][tx << 2];
            float aa[4] = {a.x, a.y, a.z, a.w};
            float bb[4] = {b.x, b.y, b.z, b.w};
            #pragma unroll
            for (int i = 0; i < 4; ++i)
                #pragma unroll
                for (int j = 0; j < 4; ++j)
                    acc[i][j] = fmaf(aa[i], bb[j], acc[i][j]);
        }
    }
    #pragma unroll
    for (int i = 0; i < 4; ++i) {
        int r = row0 + (ty << 2) + i;
        #pragma unroll
        for (int j = 0; j < 4; ++j) {
            int c = col0 + (tx << 2) + j;
            float v = acc[i][j] + bias[c];
            if (z == 0) v = -expf(v);      // store LOG decay
            C[(size_t)r * KD_ + c] = v;
        }
    }
}

// ---------------------------------------------------------------------------
// Fused split-K down-projections (z=0: w path, z=1: g path), K=2048 in 8 chunks.
__global__ __launch_bounds__(256) void gemm_f32_splitk2(const float* __restrict__ Aw,
                                                        const float* __restrict__ Ag2,
                                                        const float* __restrict__ Wwa,
                                                        const float* __restrict__ Wga,
                                                        float* __restrict__ partw,
                                                        float* __restrict__ partg) {
    __shared__ float As[16][68];
    __shared__ float Bs[16][68];
    int z = blockIdx.z;
    const float* A = z ? Ag2 : Aw;
    const float* W = z ? Wga : Wwa;
    float* part = z ? partg : partw;
    int tid = threadIdx.x;
    int tx = tid & 15, ty = tid >> 4;
    int row0 = blockIdx.y * 64;
    int kbase = blockIdx.x * 256;
    int am = tid >> 2, ak = (tid & 3) << 2;
    int bk = tid >> 4, bn = (tid & 15) << 2;
    float acc[4][4] = {};
    float4 av = *(const float4*)&A[(size_t)(row0 + am) * H_ + kbase + ak];
    float4 bv = *(const float4*)&W[(size_t)(kbase + bk) * 64 + bn];
    for (int k0 = 0; k0 < 256; k0 += 16) {
        __syncthreads();
        As[ak + 0][am] = av.x; As[ak + 1][am] = av.y;
        As[ak + 2][am] = av.z; As[ak + 3][am] = av.w;
        *(float4*)&Bs[bk][bn] = bv;
        __syncthreads();
        if (k0 + 16 < 256) {
            av = *(const float4*)&A[(size_t)(row0 + am) * H_ + kbase + k0 + 16 + ak];
            bv = *(const float4*)&W[(size_t)(kbase + k0 + 16 + bk) * 64 + bn];
        }
        #pragma unroll
        for (int kk = 0; kk < 16; ++kk) {
            float4 a = *(const float4*)&As[kk][ty << 2];
            float4 b = *(const float4*)&Bs[kk][tx << 2];
            float aa[4] = {a.x, a.y, a.z, a.w};
            float bb[4] = {b.x, b.y, b.z, b.w};
            #pragma unroll
            for (int i = 0; i < 4; ++i)
                #pragma unroll
                for (int j = 0; j < 4; ++j)
                    acc[i][j] = fmaf(aa[i], bb[j], acc[i][j]);
        }
    }
    float* pc = part + (size_t)blockIdx.x * (M_ * 64);
    #pragma unroll
    for (int i = 0; i < 4; ++i) {
        int r = row0 + (ty << 2) + i;
        #pragma unroll
        for (int j = 0; j < 4; ++j)
            pc[(size_t)r * 64 + (tx << 2) + j] = acc[i][j];
    }
}

// hid = tanh(sum_kc part[kc]) for both paths (grid y selects)
__global__ __launch_bounds__(256) void reduce_tanh2(const float* __restrict__ partw,
                                                    const float* __restrict__ partg,
                                                    float* __restrict__ hidw,
                                                    float* __restrict__ hidg) {
    int z = blockIdx.y;
    const float4* p = (const float4*)(z ? partg : partw);
    float* hid = z ? hidg : hidw;
    int i = blockIdx.x * 256 + threadIdx.x;       // 32768 float4s
    float4 s = p[i];
    #pragma unroll
    for (int kc = 1; kc < 8; ++kc) {
        float4 v = p[i + kc * 32768];
        s.x += v.x; s.y += v.y; s.z += v.z; s.w += v.w;
    }
    s.x = tanhf(s.x); s.y = tanhf(s.y); s.z = tanhf(s.z); s.w = tanhf(s.w);
    ((float4*)hid)[i] = s;
}

// ---------------------------------------------------------------------------
// Chunked scan, phase A — 512 threads (8 waves) per block for 2x latency hiding.
__global__ __launch_bounds__(512) void scan_chunkA(const float* r, const float* k,
                                                   const float* v, const float* ld,
                                                   const float* u,
                                                   float* rt, float* ointra,
                                                   float* Bc, float* Dc) {
    __shared__ float sR[CC_][68], sK[CC_][68], sV[CC_][68], sW[CC_][68];
    __shared__ float wc[CC_ + 1][64];
    __shared__ float sA[CC_][36];
    __shared__ float diag[CC_];
    __shared__ float sU[64];
    int bid = blockIdx.x;
    int bh = bid >> 5, c = bid & (NC_ - 1);
    int b = bh >> 4, h = bh & 15;
    int tid = threadIdx.x;
    size_t base = ((size_t)(b * T_ + c * CC_)) * KD_ + h * 64;

    // staging: 512 float4 slots per array, one per thread
    {
        int row = tid >> 4, col4 = (tid & 15) << 2;
        size_t gi = base + (size_t)row * KD_ + col4;
        *(float4*)&sR[row][col4] = *(const float4*)&r[gi];
        *(float4*)&sK[row][col4] = *(const float4*)&k[gi];
        *(float4*)&sV[row][col4] = *(const float4*)&v[gi];
        *(float4*)&sW[row][col4] = *(const float4*)&ld[gi];
    }
    if (tid < 64) sU[tid] = u[h * 64 + tid];
    __syncthreads();

    // prefix sum of log-decay per dk column (tid<64)
    if (tid < 64) {
        float acc = 0.f;
        wc[0][tid] = 0.f;
        #pragma unroll
        for (int s = 0; s < CC_; ++s) { acc += sW[s][tid]; wc[s + 1][tid] = acc; }
    }
    // diag[tau] = sum_i r*u*k : 16 lanes per tau, 4 elems each
    {
        int tau = tid >> 4, g = tid & 15;
        float p = 0.f;
        #pragma unroll
        for (int q = 0; q < 4; ++q) {
            int i = g * 4 + q;
            p += sR[tau][i] * sU[i] * sK[tau][i];
        }
        p += __shfl_xor(p, 1, 64); p += __shfl_xor(p, 2, 64);
        p += __shfl_xor(p, 4, 64); p += __shfl_xor(p, 8, 64);
        if (g == 0) diag[tau] = p;
    }
    __syncthreads();

    // elementwise: rt, kt, b  (4 elems per thread)
    for (int q = tid; q < CC_ * 64; q += 512) {
        int s = q >> 6, i = q & 63;
        float wcs  = wc[s][i];
        float wcs1 = wc[s + 1][i];
        float wcc  = wc[CC_][i];
        float rt_ = sR[s][i] * expf(wcs);
        float kt_ = sK[s][i] * expf(-wcs1);
        float bb  = sK[s][i] * expf(wcc - wcs1);
        sR[s][i] = rt_;
        sW[s][i] = kt_;
        sK[s][i] = bb;
        rt[base + (size_t)s * KD_ + i] = rt_;
    }
    if (tid < 64) Dc[(size_t)bid * 64 + tid] = expf(wc[CC_][tid]);
    __syncthreads();

    // score A[tau][sig]: 2 sigs per thread, K-rotated reads
    {
        int tau = tid >> 4, s0 = (tid & 15) * 2;
        float a0 = 0, a1 = 0;
        for (int i0 = 0; i0 < 64; i0 += 4) {
            int i = (i0 + ((tid & 15) << 2)) & 63;
            float4 rr  = *(const float4*)&sR[tau][i];
            float4 k0v = *(const float4*)&sW[s0 + 0][i];
            float4 k1v = *(const float4*)&sW[s0 + 1][i];
            a0 += rr.x * k0v.x + rr.y * k0v.y + rr.z * k0v.z + rr.w * k0v.w;
            a1 += rr.x * k1v.x + rr.y * k1v.y + rr.z * k1v.z + rr.w * k1v.w;
        }
        sA[tau][s0 + 0] = (s0 + 0 < tau) ? a0 : ((s0 + 0 == tau) ? diag[tau] : 0.f);
        sA[tau][s0 + 1] = (s0 + 1 < tau) ? a1 : ((s0 + 1 == tau) ? diag[tau] : 0.f);
    }
    __syncthreads();

    // o_intra[tau][j] = sum_s A[tau][s] * V[s][j]   (4 floats per thread)
    {
        int tau = tid >> 4, j0 = (tid & 15) * 4;
        float o_[4] __attribute__((aligned(16))) = {};
        for (int s = 0; s < CC_; ++s) {
            float a = sA[tau][s];
            float4 vv = *(const float4*)&sV[s][j0];
            o_[0] += a * vv.x; o_[1] += a * vv.y;
            o_[2] += a * vv.z; o_[3] += a * vv.w;
        }
        size_t ob = base + (size_t)tau * KD_ + j0;
        *(float4*)&ointra[ob] = *(float4*)&o_[0];
    }
    // B[i][j] = sum_s b[s][i] * V[s][j]   (8 floats per thread)
    {
        int i = tid >> 3, j0 = (tid & 7) * 8;
        float bacc[8] __attribute__((aligned(16))) = {};
        for (int s = 0; s < CC_; ++s) {
            float bi = sK[s][i];
            float4 v0 = *(const float4*)&sV[s][j0];
            float4 v1 = *(const float4*)&sV[s][j0 + 4];
            bacc[0] += bi * v0.x; bacc[1] += bi * v0.y;
            bacc[2] += bi * v0.z; bacc[3] += bi * v0.w;
            bacc[4] += bi * v1.x; bacc[5] += bi * v1.y;
            bacc[6] += bi * v1.z; bacc[7] += bi * v1.w;
        }
        size_t bb = ((size_t)bid << 12) + i * 64 + j0;
        *(float4*)&Bc[bb + 0] = *(float4*)&bacc[0];
        *(float4*)&Bc[bb + 4] = *(float4*)&bacc[4];
    }
}

// ---------------------------------------------------------------------------
// Phase B with next-iteration prefetch (hides load latency one step ahead).
__global__ __launch_bounds__(256) void scan_chunkB(float* BS, const float* __restrict__ Dc) {
    int g = blockIdx.x * 256 + threadIdx.x;
    int bh = g >> 12, ij = g & 4095, i = ij >> 6;
    float S = 0.f;
    size_t base = ((size_t)bh << 17) + ij;
    float bv = BS[base];
    float d  = Dc[(size_t)(bh * NC_) * 64 + i];
    for (int c = 0; c < NC_; ++c) {
        size_t idx = base + ((size_t)c << 12);
        float bv2 = 0.f, d2 = 0.f;
        if (c + 1 < NC_) {
            bv2 = BS[idx + 4096];
            d2  = Dc[(size_t)(bh * NC_ + c + 1) * 64 + i];
        }
        BS[idx] = S;
        S = d * S + bv;
        bv = bv2; d = d2;
    }
}

// ---------------------------------------------------------------------------
// Phase C fused with per-head LN + swish gate -> tiled bf16 A-layout.
// 512 threads (8 waves): 16 lanes per output row, 4 cols each.
__global__ __launch_bounds__(512) void scan_chunkC_ln(const float* __restrict__ rt,
                                                      const float* __restrict__ BS,
                                                      const float* __restrict__ oi,
                                                      const float* __restrict__ gb,
                                                      const float* __restrict__ lw,
                                                      const float* __restrict__ lb,
                                                      ushort* __restrict__ outt) {
    __shared__ float sS[64][64];
    __shared__ float sRt[CC_][68];
    int bid = blockIdx.x;
    int bh = bid >> 5, c = bid & (NC_ - 1);
    int b = bh >> 4, h = bh & 15;
    int tid = threadIdx.x;
    size_t sbase = ((size_t)bid) << 12;
    for (int q = tid; q < 1024; q += 512)
        *(float4*)&sS[q >> 4][(q & 15) << 2] = *(const float4*)&BS[sbase + (q << 2)];
    size_t base = ((size_t)(b * T_ + c * CC_)) * KD_ + h * 64;
    {
        int row = tid >> 4, col4 = (tid & 15) << 2;
        *(float4*)&sRt[row][col4] = *(const float4*)&rt[base + (size_t)row * KD_ + col4];
    }
    __syncthreads();
    int tau = tid >> 4, j0 = (tid & 15) * 4;
    size_t obase = base + (size_t)tau * KD_ + j0;
    float acc[4] __attribute__((aligned(16)));
    *(float4*)&acc[0] = *(const float4*)&oi[obase];
    for (int i = 0; i < 64; ++i) {
        float a = sRt[tau][i];
        float4 vv = *(const float4*)&sS[i][j0];
        acc[0] += a * vv.x; acc[1] += a * vv.y;
        acc[2] += a * vv.z; acc[3] += a * vv.w;
    }
    // layernorm over the 16-lane group (row of 64)
    float s = acc[0] + acc[1] + acc[2] + acc[3];
    s += __shfl_xor(s, 1, 64); s += __shfl_xor(s, 2, 64);
    s += __shfl_xor(s, 4, 64); s += __shfl_xor(s, 8, 64);
    float mean = s * (1.f / 64.f);
    float s2 = 0.f;
    #pragma unroll
    for (int q = 0; q < 4; ++q) { float dx = acc[q] - mean; s2 += dx * dx; }
    s2 += __shfl_xor(s2, 1, 64); s2 += __shfl_xor(s2, 2, 64);
    s2 += __shfl_xor(s2, 4, 64); s2 += __shfl_xor(s2, 8, 64);
    float inv = rsqrtf(s2 * (1.f / 64.f) + 1e-5f);
    float4 lwv = *(const float4*)&lw[j0];
    float4 lbv = *(const float4*)&lb[j0];
    float4 gv  = *(const float4*)&gb[obase];
    float lww[4] = {lwv.x, lwv.y, lwv.z, lwv.w};
    float lbb[4] = {lbv.x, lbv.y, lbv.z, lbv.w};
    float gvv[4] = {gv.x, gv.y, gv.z, gv.w};
    ushort o4[4];
    #pragma unroll
    for (int q = 0; q < 4; ++q) {
        float on = (acc[q] - mean) * inv * lww[q] + lbb[q];
        float g = gvv[q];
        o4[q] = bf16r(on * g / (1.f + expf(-g)));
    }
    int mrow = b * T_ + c * CC_ + tau;
    int col  = h * 64 + j0;
    int rb2 = mrow >> 7, kb2 = col >> 5, gg = (col >> 3) & 3;
    *(ushort4*)&outt[(((size_t)(rb2 * 32 + kb2)) << 12) + ((gg << 7) + (mrow & 127)) * 8 + (col & 7)] = *(ushort4*)o4;
}

// ---------------------------------------------------------------------------
extern "C" void kernel_launch(void* const* d_in, const int* in_sizes, int n_in,
                              void* d_out, int out_size, void* d_ws, size_t ws_size,
                              hipStream_t stream) {
    const float* x     = (const float*)d_in[0];
    const float* mu_x  = (const float*)d_in[1];
    const float* Wx1   = (const float*)d_in[2];
    const float* Wx2   = (const float*)d_in[3];
    const float* xbias = (const float*)d_in[4];
    const float* Wr    = (const float*)d_in[5];
    const float* Wk    = (const float*)d_in[6];
    const float* Wv    = (const float*)d_in[7];
    const float* Ww_a  = (const float*)d_in[8];
    const float* Ww_b  = (const float*)d_in[9];
    const float* bw    = (const float*)d_in[10];
    const float* Wg_a  = (const float*)d_in[11];
    const float* Wg_b  = (const float*)d_in[12];
    const float* bg    = (const float*)d_in[13];
    const float* bonus = (const float*)d_in[14];
    const float* ln_w  = (const float*)d_in[15];
    const float* ln_b  = (const float*)d_in[16];
    const float* Wo    = (const float*)d_in[17];
    float* out = (float*)d_out;

    // workspace layout (float units), with overlays (see launch order)
    float* ws   = (float*)d_ws;
    float* xm   = ws;                               // 4M floats: xmt_r|xmt_k; later gt
    float* lr   = xm   + (size_t)M_ * H_;           // lrt | wx2t (bf16 overlays)
    float* hidw = lr   + (size_t)M_ * 320;          // M_*64
    float* hidg = hidw + (size_t)M_ * 64;           // M_*64
    float* rb_  = hidg + (size_t)M_ * 64;           // M_*KD_ ; xm_w spans rb_..kb_
    float* kb_  = rb_  + (size_t)M_ * KD_;
    float* vb_  = kb_  + (size_t)M_ * KD_;          // xm_g spans vb_..db_
    float* db_  = vb_  + (size_t)M_ * KD_;
    float* gb_  = db_  + (size_t)M_ * KD_;          // first 1M floats double as part_g
    float* ob_  = gb_  + (size_t)M_ * KD_;
    float* BS   = ob_  + (size_t)M_ * KD_;          // 4M floats: part_w | xmt_v | scan B/S
    float* Dc   = BS   + (size_t)1024 * 4096;       // 1024*64
    float* wend = Dc + (size_t)1024 * 64;
    // bf16 overlays (ushort units)
    ushort* xmt_r = (ushort*)xm;                            // 8 MB
    ushort* xmt_k = (ushort*)(xm + (size_t)M_ * H_ / 2);    // 8 MB
    ushort* xmt_v = (ushort*)(BS + 1310720);                // 8 MB (past 4MB part_w)
    float*  xm_w  = rb_;                                    // 16 MB fp32
    float*  xm_g  = vb_;                                    // 16 MB fp32
    float*  partw = BS;                                     // 4 MB (step 3 only)
    float*  partg = gb_;                                    // 4 MB (step 3 only)
    ushort* gt    = (ushort*)xm;                            // 4 MB
    ushort* lrt   = (ushort*)lr;                            // 16*5*8192 = 655360 ush
    ushort* wx2t  = lrt + 655360;                           // 5*32*2*2048 = 655360 ush
    ushort* Wx1t  = (ushort*)wend;                          // 2048*320
    ushort* Wrt   = Wx1t + (size_t)H_ * 320;
    ushort* Wkt   = Wrt  + (size_t)H_ * KD_;
    ushort* Wvt   = Wkt  + (size_t)H_ * KD_;
    ushort* Wot   = Wvt  + (size_t)H_ * KD_;                // 1024*2048

    dim3 blk(256);
    const int elems8 = M_ * H_ / 8;

    // 0. weight conversions (tiled bf16)
    convert_w<<<dim3(320 / 64, H_ / 32), blk, 0, stream>>>(Wx1, Wx1t, H_, 320);
    convert_w3<<<dim3(KD_ / 64, H_ / 32, 3), blk, 0, stream>>>(Wr, Wk, Wv, Wrt);
    convert_w<<<dim3(H_ / 64, KD_ / 32), blk, 0, stream>>>(Wo, Wot, KD_, H_);
    convert_wx2<<<dim3(32, 5), blk, 0, stream>>>(Wx2, wx2t);

    // 1. lrt = tanh((x + delta*mu_x) @ Wx1) as bf16 A-tiled per branch [MFMA, BK=64]
    mix_mu_t<<<elems8 / 256, blk, 0, stream>>>(x, mu_x, (ushort*)xm);
    gemm_bf16t_lr<<<dim3(5, M_ / 128), blk, 0, stream>>>((ushort*)xm, Wx1t, lrt);

    // 2. MFMA mus-GEMM + lerp (K=64, branch on z; 2560 blocks)
    musgemm_mfma<<<dim3(H_ / 64, M_ / 128, 5), blk, 0, stream>>>(lrt, wx2t, x, xbias,
                                                                 xmt_r, xm_w, xmt_k, xmt_v, xm_g);

    // 3. LoRA down-projections (split-K z=2) + tanh reduce (z=2)
    gemm_f32_splitk2<<<dim3(8, M_ / 64, 2), blk, 0, stream>>>(xm_w, xm_g, Ww_a, Wg_a,
                                                              partw, partg);
    reduce_tanh2<<<dim3(128, 2), blk, 0, stream>>>(partw, partg, hidw, hidg);

    // 4. LoRA up-projections (z=2): log-decay and raw gate
    gemm_f32_up2<<<dim3(KD_ / 64, M_ / 64, 2), blk, 0, stream>>>(hidw, hidg, Ww_b, Wg_b,
                                                                 bw, bg, db_, gb_);

    // 5. r/k/v projections fused [bf16 MFMA, BK=64], 768 blocks, XCD-swizzled
    gemm_bf16t<0, 3><<<dim3(KD_ / 64, M_ / 128, 3), blk, 0, stream>>>(xmt_r, xmt_k, xmt_v,
                                                                      Wrt, rb_, H_, KD_);

    // 6. chunk-parallel scan; phases A and C at 512 threads (8 waves, 2x TLP)
    scan_chunkA<<<B_ * NH_ * NC_, dim3(512), 0, stream>>>(rb_, kb_, vb_, db_, bonus,
                                                          rb_ /*rt in place*/, ob_, BS, Dc);
    scan_chunkB<<<(B_ * NH_ * 4096) / 256, blk, 0, stream>>>(BS, Dc);
    scan_chunkC_ln<<<B_ * NH_ * NC_, dim3(512), 0, stream>>>(rb_, BS, ob_, gb_, ln_w, ln_b, gt);

    // 7. out = gated @ Wo  [bf16 MFMA, BK=64], 512 blocks, XCD-swizzled
    gemm_bf16t<0, 1><<<dim3(H_ / 64, M_ / 128), blk, 0, stream>>>(gt, nullptr, nullptr,
                                                                  Wot, out, KD_, H_);
}

// Round 22
// 228.010 us; speedup vs baseline: 1.0238x; 1.0238x over previous
//
#include <hip/hip_runtime.h>
#include <hip/hip_bf16.h>

#define H_    2048
#define NH_   16
#define KD_   1024
#define DK_   64
#define T_    1024
#define B_    2
#define M_    (B_*T_)     // 2048 rows
#define RL_   64
#define CC_   32          // scan chunk length
#define NC_   (T_/CC_)    // 32 chunks per sequence

typedef short bf16x8 __attribute__((ext_vector_type(8)));   // 8 bf16 (4 VGPR)
typedef float f32x4  __attribute__((ext_vector_type(4)));   // MFMA acc

__device__ __forceinline__ ushort bf16r(float f) {          // RNE fp32->bf16
    union { float f; unsigned u; } v; v.f = f;
    return (ushort)((v.u + 0x7FFF + ((v.u >> 16) & 1)) >> 16);
}

// async global->LDS, 16B per lane; lds base must be wave-uniform
__device__ __forceinline__ void gl_lds16(const void* g, void* l) {
    __builtin_amdgcn_global_load_lds((const __attribute__((address_space(1))) void*)g,
                                     (__attribute__((address_space(3))) void*)l, 16, 0, 0);
}

// XCD-aware bijective block swizzle (requires nwg % 8 == 0)
__device__ __forceinline__ void xcd_swz(int& bx, int& by, int& bz) {
    int gx = gridDim.x, gy = gridDim.y;
    int nwg = gx * gy * gridDim.z;
    int bid = ((int)blockIdx.z * gy + blockIdx.y) * gx + blockIdx.x;
    int swz = (bid & 7) * (nwg >> 3) + (bid >> 3);
    bx = swz % gx;
    int rem = swz / gx;
    by = rem % gy;
    bz = rem / gy;
}

// ---------------------------------------------------------------------------
// Tiled bf16 layouts:
//  A-tiles (BM=128, BK=32): 4096 bf16/tile, elem (r,k): off = (g*128+r)*8+(k&7), g=(k>>3)&3
//  B-tiles (BN=64, BK=32): 2048 bf16/tile, elem (c,k): off = (g*64+c)*8+(k&7)
// ---------------------------------------------------------------------------

// W [K][N] fp32 -> tiled bf16 B-layout for one (kb, nb) 32x64 block
__device__ __forceinline__ void conv_body(const float* __restrict__ W,
                                          ushort* __restrict__ Wt,
                                          int K, int N, int kb, int nb,
                                          float (*s)[68], int t) {
    #pragma unroll
    for (int i = 0; i < 2; ++i) {
        int q = t + i * 256;
        int k = q >> 4, c4 = (q & 15) << 2;
        *(float4*)&s[k][c4] = *(const float4*)&W[(size_t)(kb * 32 + k) * N + nb * 64 + c4];
    }
    __syncthreads();
    int g = t >> 6, c = t & 63;
    ushort o[8];
    #pragma unroll
    for (int e = 0; e < 8; ++e) o[e] = bf16r(s[g * 8 + e][c]);
    *(uint4*)&Wt[((size_t)(nb * (K >> 5) + kb)) * 2048 + t * 8] = *(uint4*)o;
}

// ---------------------------------------------------------------------------
// Fused preprocessing: mix_mu (xx -> bf16 A-tiled) + all weight conversions.
// Block ranges: [0,2048) mix | [2048,2368) Wx1 | [2368,5440) r/k/v |
//               [5440,6464) Wo | [6464,6624) Wx2
__global__ __launch_bounds__(256) void prep_all(const float* __restrict__ x,
                                                const float* __restrict__ mu,
                                                const float* __restrict__ Wx1,
                                                const float* __restrict__ W0,
                                                const float* __restrict__ W1,
                                                const float* __restrict__ W2,
                                                const float* __restrict__ Wo,
                                                const float* __restrict__ Wx2,
                                                ushort* __restrict__ At,
                                                ushort* __restrict__ Wx1t,
                                                ushort* __restrict__ Wrt,
                                                ushort* __restrict__ Wot,
                                                ushort* __restrict__ wx2t) {
    __shared__ float s[64][68];
    int bid = blockIdx.x;
    int tid = threadIdx.x;
    if (bid < 2048) {                      // ---- mix_mu ----
        int c = bid * 256 + tid;
        int bt = c >> 8, k8 = c & 255;
        int k = k8 << 3;
        int t = bt & (T_ - 1);
        const float* xp = &x[(size_t)bt * H_ + k];
        float4 xa = *(const float4*)xp;
        float4 xb = *(const float4*)(xp + 4);
        float4 sa = make_float4(0,0,0,0), sb = make_float4(0,0,0,0);
        if (t > 0) { sa = *(const float4*)(xp - H_); sb = *(const float4*)(xp - H_ + 4); }
        float4 ma = *(const float4*)&mu[k];
        float4 mb = *(const float4*)&mu[k + 4];
        ushort o[8];
        o[0] = bf16r(xa.x + (sa.x - xa.x) * ma.x);
        o[1] = bf16r(xa.y + (sa.y - xa.y) * ma.y);
        o[2] = bf16r(xa.z + (sa.z - xa.z) * ma.z);
        o[3] = bf16r(xa.w + (sa.w - xa.w) * ma.w);
        o[4] = bf16r(xb.x + (sb.x - xb.x) * mb.x);
        o[5] = bf16r(xb.y + (sb.y - xb.y) * mb.y);
        o[6] = bf16r(xb.z + (sb.z - xb.z) * mb.z);
        o[7] = bf16r(xb.w + (sb.w - xb.w) * mb.w);
        int rb = bt >> 7, kb = k8 >> 2, g = k8 & 3, r = bt & 127;
        *(uint4*)&At[(((size_t)(rb * 64 + kb)) << 12) + ((g << 7) + r) * 8] = *(uint4*)o;
        return;
    }
    bid -= 2048;
    if (bid < 320) {                       // ---- convert Wx1 [2048][320] ----
        conv_body(Wx1, Wx1t, H_, 320, bid / 5, bid % 5, s, tid);
        return;
    }
    bid -= 320;
    if (bid < 3072) {                      // ---- convert Wr/Wk/Wv ----
        int nb = bid & 15, kb = (bid >> 4) & 63, z = bid >> 10;
        const float* W = (z == 0) ? W0 : (z == 1) ? W1 : W2;
        conv_body(W, Wrt + (size_t)z * ((size_t)H_ * KD_), H_, KD_, kb, nb, s, tid);
        return;
    }
    bid -= 3072;
    if (bid < 1024) {                      // ---- convert Wo [1024][2048] ----
        conv_body(Wo, Wot, KD_, H_, bid >> 5, bid & 31, s, tid);
        return;
    }
    bid -= 1024;
    {                                      // ---- convert Wx2 per-branch ----
        int nb = bid & 31, z = bid >> 5;
        for (int q = tid; q < 1024; q += 256) {
            int row = q >> 4, c4 = (q & 15) << 2;
            *(float4*)&s[row][c4] = *(const float4*)&Wx2[(size_t)(nb * 64 + row) * 320 + z * 64 + c4];
        }
        __syncthreads();
        for (int q = tid; q < 512; q += 256) {
            int kb = q >> 8, i = q & 255;
            int g = i >> 6, c = i & 63;
            ushort o[8];
            #pragma unroll
            for (int e = 0; e < 8; ++e) o[e] = bf16r(s[c][kb * 32 + g * 8 + e]);
            *(uint4*)&wx2t[(((size_t)(z * 32 + nb)) * 2 + kb) * 2048 + i * 8] = *(uint4*)o;
        }
    }
}

// ---------------------------------------------------------------------------
// bf16 MFMA GEMM, BM=128 x BN=64, BK=64 (two 32-K subtiles per iteration).
// Double-buffered global_load_lds staging, XCD-swizzled grid.
// NB>1: z selects branch. EPI: 0 = none, 1 = tanh
template<int EPI, int NB>
__global__ __launch_bounds__(256) void gemm_bf16t(const ushort* __restrict__ A0,
                                                  const ushort* __restrict__ A1,
                                                  const ushort* __restrict__ A2,
                                                  const ushort* __restrict__ Bt0,
                                                  float* __restrict__ C0,
                                                  int K, int ldc) {
    __shared__ ushort Alds[2][8192];
    __shared__ ushort Blds[2][4096];
    int bx, by, bz;
    xcd_swz(bx, by, bz);
    int tid = threadIdx.x;
    int w = tid >> 6, l = tid & 63;
    int KB32 = K >> 5;           // 32-K tiles (addressing)
    int KB64 = K >> 6;           // loop iterations
    int z = (NB > 1) ? bz : 0;
    const ushort* At = (NB > 1) ? (z == 0 ? A0 : z == 1 ? A1 : A2) : A0;
    const ushort* Bt = Bt0 + (size_t)z * ((size_t)H_ * KD_);
    float* C = C0 + (size_t)z * ((size_t)M_ * KD_);
    const ushort* Ag = At + (size_t)by * KB32 * 4096 + tid * 8;
    const ushort* Bg = Bt + (size_t)bx * KB32 * 2048 + tid * 8;
    int wr = (w >> 1) << 6, wc = (w & 1) << 5;
    int a_off = (((l >> 4) << 7) + wr + (l & 15)) << 3;
    int b_off = (((l >> 4) << 6) + wc + (l & 15)) << 3;
    f32x4 acc[8] = {};
    #pragma unroll
    for (int j = 0; j < 4; ++j) gl_lds16(Ag + j * 2048, &Alds[0][w * 512 + j * 2048]);
    #pragma unroll
    for (int j = 0; j < 2; ++j) gl_lds16(Bg + j * 2048, &Blds[0][w * 512 + j * 2048]);
    __syncthreads();
    for (int kt = 0; kt < KB64; ++kt) {
        int cur = kt & 1;
        if (kt + 1 < KB64) {
            Ag += 8192; Bg += 4096;
            int nxt = cur ^ 1;
            #pragma unroll
            for (int j = 0; j < 4; ++j) gl_lds16(Ag + j * 2048, &Alds[nxt][w * 512 + j * 2048]);
            #pragma unroll
            for (int j = 0; j < 2; ++j) gl_lds16(Bg + j * 2048, &Blds[nxt][w * 512 + j * 2048]);
        }
        #pragma unroll
        for (int kb2 = 0; kb2 < 2; ++kb2) {
            const ushort* Ab = &Alds[cur][kb2 * 4096 + a_off];
            const ushort* Bb = &Blds[cur][kb2 * 2048 + b_off];
            bf16x8 af0 = *(const bf16x8*)(Ab);
            bf16x8 af1 = *(const bf16x8*)(Ab + 128);
            bf16x8 af2 = *(const bf16x8*)(Ab + 256);
            bf16x8 af3 = *(const bf16x8*)(Ab + 384);
            bf16x8 bf0 = *(const bf16x8*)(Bb);
            bf16x8 bf1 = *(const bf16x8*)(Bb + 128);
            acc[0] = __builtin_amdgcn_mfma_f32_16x16x32_bf16(af0, bf0, acc[0], 0, 0, 0);
            acc[1] = __builtin_amdgcn_mfma_f32_16x16x32_bf16(af0, bf1, acc[1], 0, 0, 0);
            acc[2] = __builtin_amdgcn_mfma_f32_16x16x32_bf16(af1, bf0, acc[2], 0, 0, 0);
            acc[3] = __builtin_amdgcn_mfma_f32_16x16x32_bf16(af1, bf1, acc[3], 0, 0, 0);
            acc[4] = __builtin_amdgcn_mfma_f32_16x16x32_bf16(af2, bf0, acc[4], 0, 0, 0);
            acc[5] = __builtin_amdgcn_mfma_f32_16x16x32_bf16(af2, bf1, acc[5], 0, 0, 0);
            acc[6] = __builtin_amdgcn_mfma_f32_16x16x32_bf16(af3, bf0, acc[6], 0, 0, 0);
            acc[7] = __builtin_amdgcn_mfma_f32_16x16x32_bf16(af3, bf1, acc[7], 0, 0, 0);
        }
        __syncthreads();
    }
    int row0 = (by << 7) + wr + ((l >> 4) << 2);
    int col0 = (bx << 6) + wc + (l & 15);
    #pragma unroll
    for (int fr = 0; fr < 4; ++fr)
        #pragma unroll
        for (int fc = 0; fc < 2; ++fc) {
            f32x4 v = acc[fr * 2 + fc];
            #pragma unroll
            for (int q = 0; q < 4; ++q) {
                float o = v[q];
                if (EPI == 1) o = tanhf(o);
                C[(size_t)(row0 + fr * 16 + q) * ldc + col0 + fc * 16] = o;
            }
        }
}

// ---------------------------------------------------------------------------
// Wx1 GEMM variant: K=2048, BK=64, grid (branch=5, rb=16), XCD-swizzled;
// epilogue writes lr = tanh(acc) as bf16 A-fragment-tiled lrt (K=64/branch).
__global__ __launch_bounds__(256) void gemm_bf16t_lr(const ushort* __restrict__ At,
                                                     const ushort* __restrict__ Bt,
                                                     ushort* __restrict__ lrt) {
    __shared__ ushort Alds[2][8192];
    __shared__ ushort Blds[2][4096];
    int bx, by, bz;
    xcd_swz(bx, by, bz);
    int tid = threadIdx.x;
    int w = tid >> 6, l = tid & 63;
    const int KB32 = H_ >> 5;   // 64 tiles
    const int KB64 = H_ >> 6;   // 32 iterations
    const ushort* Ag = At + (size_t)by * KB32 * 4096 + tid * 8;
    const ushort* Bg = Bt + (size_t)bx * KB32 * 2048 + tid * 8;
    int wr = (w >> 1) << 6, wc = (w & 1) << 5;
    int a_off = (((l >> 4) << 7) + wr + (l & 15)) << 3;
    int b_off = (((l >> 4) << 6) + wc + (l & 15)) << 3;
    f32x4 acc[8] = {};
    #pragma unroll
    for (int j = 0; j < 4; ++j) gl_lds16(Ag + j * 2048, &Alds[0][w * 512 + j * 2048]);
    #pragma unroll
    for (int j = 0; j < 2; ++j) gl_lds16(Bg + j * 2048, &Blds[0][w * 512 + j * 2048]);
    __syncthreads();
    for (int kt = 0; kt < KB64; ++kt) {
        int cur = kt & 1;
        if (kt + 1 < KB64) {
            Ag += 8192; Bg += 4096;
            int nxt = cur ^ 1;
            #pragma unroll
            for (int j = 0; j < 4; ++j) gl_lds16(Ag + j * 2048, &Alds[nxt][w * 512 + j * 2048]);
            #pragma unroll
            for (int j = 0; j < 2; ++j) gl_lds16(Bg + j * 2048, &Blds[nxt][w * 512 + j * 2048]);
        }
        #pragma unroll
        for (int kb2 = 0; kb2 < 2; ++kb2) {
            const ushort* Ab = &Alds[cur][kb2 * 4096 + a_off];
            const ushort* Bb = &Blds[cur][kb2 * 2048 + b_off];
            bf16x8 af0 = *(const bf16x8*)(Ab);
            bf16x8 af1 = *(const bf16x8*)(Ab + 128);
            bf16x8 af2 = *(const bf16x8*)(Ab + 256);
            bf16x8 af3 = *(const bf16x8*)(Ab + 384);
            bf16x8 bf0 = *(const bf16x8*)(Bb);
            bf16x8 bf1 = *(const bf16x8*)(Bb + 128);
            acc[0] = __builtin_amdgcn_mfma_f32_16x16x32_bf16(af0, bf0, acc[0], 0, 0, 0);
            acc[1] = __builtin_amdgcn_mfma_f32_16x16x32_bf16(af0, bf1, acc[1], 0, 0, 0);
            acc[2] = __builtin_amdgcn_mfma_f32_16x16x32_bf16(af1, bf0, acc[2], 0, 0, 0);
            acc[3] = __builtin_amdgcn_mfma_f32_16x16x32_bf16(af1, bf1, acc[3], 0, 0, 0);
            acc[4] = __builtin_amdgcn_mfma_f32_16x16x32_bf16(af2, bf0, acc[4], 0, 0, 0);
            acc[5] = __builtin_amdgcn_mfma_f32_16x16x32_bf16(af2, bf1, acc[5], 0, 0, 0);
            acc[6] = __builtin_amdgcn_mfma_f32_16x16x32_bf16(af3, bf0, acc[6], 0, 0, 0);
            acc[7] = __builtin_amdgcn_mfma_f32_16x16x32_bf16(af3, bf1, acc[7], 0, 0, 0);
        }
        __syncthreads();
    }
    int rloc0 = wr + ((l >> 4) << 2);              // local row in [0,128)
    size_t tbase = ((size_t)(by * 5 + bx)) * 8192;
    #pragma unroll
    for (int fr = 0; fr < 4; ++fr)
        #pragma unroll
        for (int fc = 0; fc < 2; ++fc) {
            f32x4 v = acc[fr * 2 + fc];
            int c = wc + fc * 16 + (l & 15);       // branch-local K index [0,64)
            int kb2 = c >> 5, g = (c >> 3) & 3, e = c & 7;
            #pragma unroll
            for (int q = 0; q < 4; ++q) {
                int r = rloc0 + fr * 16 + q;
                lrt[tbase + (size_t)kb2 * 4096 + ((g << 7) + r) * 8 + e] = bf16r(tanhf(v[q]));
            }
        }
}

// ---------------------------------------------------------------------------
// MFMA mus-GEMM + lerp: C = lrt @ Wx2t (K=64) per branch z; epilogue applies
// bias + lerp vs x/shift and writes branch-specific outputs.
__global__ __launch_bounds__(256) void musgemm_mfma(const ushort* __restrict__ lrt,
                                                    const ushort* __restrict__ wx2t,
                                                    const float* __restrict__ x,
                                                    const float* __restrict__ xbias,
                                                    ushort* __restrict__ xmt_r,
                                                    float*  __restrict__ xm_w,
                                                    ushort* __restrict__ xmt_k,
                                                    ushort* __restrict__ xmt_v,
                                                    float*  __restrict__ xm_g) {
    __shared__ ushort Alds[8192];
    __shared__ ushort Blds[4096];
    int tid = threadIdx.x;
    int w = tid >> 6, l = tid & 63;
    int z = blockIdx.z;
    const ushort* Ag = lrt + ((size_t)(blockIdx.y * 5 + z)) * 8192 + tid * 8;
    const ushort* Bg = wx2t + ((size_t)(z * 32 + blockIdx.x)) * 4096 + tid * 8;
    gl_lds16(Ag,        &Alds[w * 512]);
    gl_lds16(Ag + 2048, &Alds[w * 512 + 2048]);
    gl_lds16(Ag + 4096, &Alds[w * 512 + 4096]);
    gl_lds16(Ag + 6144, &Alds[w * 512 + 6144]);
    gl_lds16(Bg,        &Blds[w * 512]);
    gl_lds16(Bg + 2048, &Blds[w * 512 + 2048]);
    int wr = (w >> 1) << 6, wc = (w & 1) << 5;
    int a_off = (((l >> 4) << 7) + wr + (l & 15)) << 3;
    int b_off = (((l >> 4) << 6) + wc + (l & 15)) << 3;
    f32x4 acc[8] = {};
    __syncthreads();
    #pragma unroll
    for (int kb = 0; kb < 2; ++kb) {
        const ushort* Ab = &Alds[kb * 4096 + a_off];
        const ushort* Bb = &Blds[kb * 2048 + b_off];
        bf16x8 af0 = *(const bf16x8*)(Ab);
        bf16x8 af1 = *(const bf16x8*)(Ab + 128);
        bf16x8 af2 = *(const bf16x8*)(Ab + 256);
        bf16x8 af3 = *(const bf16x8*)(Ab + 384);
        bf16x8 bf0 = *(const bf16x8*)(Bb);
        bf16x8 bf1 = *(const bf16x8*)(Bb + 128);
        acc[0] = __builtin_amdgcn_mfma_f32_16x16x32_bf16(af0, bf0, acc[0], 0, 0, 0);
        acc[1] = __builtin_amdgcn_mfma_f32_16x16x32_bf16(af0, bf1, acc[1], 0, 0, 0);
        acc[2] = __builtin_amdgcn_mfma_f32_16x16x32_bf16(af1, bf0, acc[2], 0, 0, 0);
        acc[3] = __builtin_amdgcn_mfma_f32_16x16x32_bf16(af1, bf1, acc[3], 0, 0, 0);
        acc[4] = __builtin_amdgcn_mfma_f32_16x16x32_bf16(af2, bf0, acc[4], 0, 0, 0);
        acc[5] = __builtin_amdgcn_mfma_f32_16x16x32_bf16(af2, bf1, acc[5], 0, 0, 0);
        acc[6] = __builtin_amdgcn_mfma_f32_16x16x32_bf16(af3, bf0, acc[6], 0, 0, 0);
        acc[7] = __builtin_amdgcn_mfma_f32_16x16x32_bf16(af3, bf1, acc[7], 0, 0, 0);
    }
    int row0 = (blockIdx.y << 7) + wr + ((l >> 4) << 2);
    int col0 = (blockIdx.x << 6) + wc + (l & 15);
    #pragma unroll
    for (int fr = 0; fr < 4; ++fr)
        #pragma unroll
        for (int fc = 0; fc < 2; ++fc) {
            f32x4 v = acc[fr * 2 + fc];
            int h = col0 + fc * 16;
            float bias = xbias[z * H_ + h];
            #pragma unroll
            for (int q = 0; q < 4; ++q) {
                int r = row0 + fr * 16 + q;
                int t = r & (T_ - 1);
                const float* xp = &x[(size_t)r * H_ + h];
                float xv = *xp;
                float sh = (t > 0) ? *(xp - H_) : 0.f;
                float o = xv + (sh - xv) * (v[q] + bias);
                if (z == 0 || z == 2 || z == 3) {
                    ushort* dst = (z == 0) ? xmt_r : (z == 2) ? xmt_k : xmt_v;
                    int rb = r >> 7, kb = h >> 5, g = (h >> 3) & 3;
                    dst[(((size_t)(rb * 64 + kb)) << 12) + ((g << 7) + (r & 127)) * 8 + (h & 7)] = bf16r(o);
                } else {
                    float* dst = (z == 1) ? xm_w : xm_g;
                    dst[(size_t)r * H_ + h] = o;
                }
            }
        }
}

// ---------------------------------------------------------------------------
// Fused LoRA up-projections (z=0: decay path, z=1: gate path), K=64.
__global__ __launch_bounds__(256) void gemm_f32_up2(const float* __restrict__ hidw,
                                                    const float* __restrict__ hidg,
                                                    const float* __restrict__ Wwb,
                                                    const float* __restrict__ Wgb,
                                                    const float* __restrict__ bw,
                                                    const float* __restrict__ bg,
                                                    float* __restrict__ db,
                                                    float* __restrict__ gb) {
    __shared__ float As[16][68];
    __shared__ float Bs[16][68];
    int z = blockIdx.z;
    const float* A = z ? hidg : hidw;
    const float* W = z ? Wgb : Wwb;
    const float* bias = z ? bg : bw;
    float* C = z ? gb : db;
    int tid = threadIdx.x;
    int tx = tid & 15, ty = tid >> 4;
    int row0 = blockIdx.y * 64, col0 = blockIdx.x * 64;
    int am = tid >> 2, ak = (tid & 3) << 2;
    int bk = tid >> 4, bn = (tid & 15) << 2;
    float acc[4][4] = {};
    float4 av = *(const float4*)&A[(size_t)(row0 + am) * 64 + ak];
    float4 bv = *(const float4*)&W[(size_t)bk * KD_ + col0 + bn];
    for (int k0 = 0; k0 < 64; k0 += 16) {
        __syncthreads();
        As[ak + 0][am] = av.x; As[ak + 1][am] = av.y;
        As[ak + 2][am] = av.z; As[ak + 3][am] = av.w;
        *(float4*)&Bs[bk][bn] = bv;
        __syncthreads();
        if (k0 + 16 < 64) {
            av = *(const float4*)&A[(size_t)(row0 + am) * 64 + k0 + 16 + ak];
            bv = *(const float4*)&W[(size_t)(k0 + 16 + bk) * KD_ + col0 + bn];
        }
        #pragma unroll
        for (int kk = 0; kk < 16; ++kk) {
            float4 a = *(const float4*)&As[kk][ty << 2];
            float4 b = *(const float4*)&Bs[kk][tx << 2];
            float aa[4] = {a.x, a.y, a.z, a.w};
            float bb[4] = {b.x, b.y, b.z, b.w};
            #pragma unroll
            for (int i = 0; i < 4; ++i)
                #pragma unroll
                for (int j = 0; j < 4; ++j)
                    acc[i][j] = fmaf(aa[i], bb[j], acc[i][j]);
        }
    }
    #pragma unroll
    for (int i = 0; i < 4; ++i) {
        int r = row0 + (ty << 2) + i;
        #pragma unroll
        for (int j = 0; j < 4; ++j) {
            int c = col0 + (tx << 2) + j;
            float v = acc[i][j] + bias[c];
            if (z == 0) v = -expf(v);      // store LOG decay
            C[(size_t)r * KD_ + c] = v;
        }
    }
}

// ---------------------------------------------------------------------------
// Fused split-K down-projections (z=0: w path, z=1: g path), K=2048 in 8 chunks.
__global__ __launch_bounds__(256) void gemm_f32_splitk2(const float* __restrict__ Aw,
                                                        const float* __restrict__ Ag2,
                                                        const float* __restrict__ Wwa,
                                                        const float* __restrict__ Wga,
                                                        float* __restrict__ partw,
                                                        float* __restrict__ partg) {
    __shared__ float As[16][68];
    __shared__ float Bs[16][68];
    int z = blockIdx.z;
    const float* A = z ? Ag2 : Aw;
    const float* W = z ? Wga : Wwa;
    float* part = z ? partg : partw;
    int tid = threadIdx.x;
    int tx = tid & 15, ty = tid >> 4;
    int row0 = blockIdx.y * 64;
    int kbase = blockIdx.x * 256;
    int am = tid >> 2, ak = (tid & 3) << 2;
    int bk = tid >> 4, bn = (tid & 15) << 2;
    float acc[4][4] = {};
    float4 av = *(const float4*)&A[(size_t)(row0 + am) * H_ + kbase + ak];
    float4 bv = *(const float4*)&W[(size_t)(kbase + bk) * 64 + bn];
    for (int k0 = 0; k0 < 256; k0 += 16) {
        __syncthreads();
        As[ak + 0][am] = av.x; As[ak + 1][am] = av.y;
        As[ak + 2][am] = av.z; As[ak + 3][am] = av.w;
        *(float4*)&Bs[bk][bn] = bv;
        __syncthreads();
        if (k0 + 16 < 256) {
            av = *(const float4*)&A[(size_t)(row0 + am) * H_ + kbase + k0 + 16 + ak];
            bv = *(const float4*)&W[(size_t)(kbase + k0 + 16 + bk) * 64 + bn];
        }
        #pragma unroll
        for (int kk = 0; kk < 16; ++kk) {
            float4 a = *(const float4*)&As[kk][ty << 2];
            float4 b = *(const float4*)&Bs[kk][tx << 2];
            float aa[4] = {a.x, a.y, a.z, a.w};
            float bb[4] = {b.x, b.y, b.z, b.w};
            #pragma unroll
            for (int i = 0; i < 4; ++i)
                #pragma unroll
                for (int j = 0; j < 4; ++j)
                    acc[i][j] = fmaf(aa[i], bb[j], acc[i][j]);
        }
    }
    float* pc = part + (size_t)blockIdx.x * (M_ * 64);
    #pragma unroll
    for (int i = 0; i < 4; ++i) {
        int r = row0 + (ty << 2) + i;
        #pragma unroll
        for (int j = 0; j < 4; ++j)
            pc[(size_t)r * 64 + (tx << 2) + j] = acc[i][j];
    }
}

// hid = tanh(sum_kc part[kc]) for both paths (grid y selects)
__global__ __launch_bounds__(256) void reduce_tanh2(const float* __restrict__ partw,
                                                    const float* __restrict__ partg,
                                                    float* __restrict__ hidw,
                                                    float* __restrict__ hidg) {
    int z = blockIdx.y;
    const float4* p = (const float4*)(z ? partg : partw);
    float* hid = z ? hidg : hidw;
    int i = blockIdx.x * 256 + threadIdx.x;       // 32768 float4s
    float4 s = p[i];
    #pragma unroll
    for (int kc = 1; kc < 8; ++kc) {
        float4 v = p[i + kc * 32768];
        s.x += v.x; s.y += v.y; s.z += v.z; s.w += v.w;
    }
    s.x = tanhf(s.x); s.y = tanhf(s.y); s.z = tanhf(s.z); s.w = tanhf(s.w);
    ((float4*)hid)[i] = s;
}

// ---------------------------------------------------------------------------
// Chunked scan, phase A — 512 threads (8 waves) per block for 2x latency hiding.
__global__ __launch_bounds__(512) void scan_chunkA(const float* r, const float* k,
                                                   const float* v, const float* ld,
                                                   const float* u,
                                                   float* rt, float* ointra,
                                                   float* Bc, float* Dc) {
    __shared__ float sR[CC_][68], sK[CC_][68], sV[CC_][68], sW[CC_][68];
    __shared__ float wc[CC_ + 1][64];
    __shared__ float sA[CC_][36];
    __shared__ float diag[CC_];
    __shared__ float sU[64];
    int bid = blockIdx.x;
    int bh = bid >> 5, c = bid & (NC_ - 1);
    int b = bh >> 4, h = bh & 15;
    int tid = threadIdx.x;
    size_t base = ((size_t)(b * T_ + c * CC_)) * KD_ + h * 64;

    // staging: 512 float4 slots per array, one per thread
    {
        int row = tid >> 4, col4 = (tid & 15) << 2;
        size_t gi = base + (size_t)row * KD_ + col4;
        *(float4*)&sR[row][col4] = *(const float4*)&r[gi];
        *(float4*)&sK[row][col4] = *(const float4*)&k[gi];
        *(float4*)&sV[row][col4] = *(const float4*)&v[gi];
        *(float4*)&sW[row][col4] = *(const float4*)&ld[gi];
    }
    if (tid < 64) sU[tid] = u[h * 64 + tid];
    __syncthreads();

    // prefix sum of log-decay per dk column (tid<64)
    if (tid < 64) {
        float acc = 0.f;
        wc[0][tid] = 0.f;
        #pragma unroll
        for (int s = 0; s < CC_; ++s) { acc += sW[s][tid]; wc[s + 1][tid] = acc; }
    }
    // diag[tau] = sum_i r*u*k : 16 lanes per tau, 4 elems each
    {
        int tau = tid >> 4, g = tid & 15;
        float p = 0.f;
        #pragma unroll
        for (int q = 0; q < 4; ++q) {
            int i = g * 4 + q;
            p += sR[tau][i] * sU[i] * sK[tau][i];
        }
        p += __shfl_xor(p, 1, 64); p += __shfl_xor(p, 2, 64);
        p += __shfl_xor(p, 4, 64); p += __shfl_xor(p, 8, 64);
        if (g == 0) diag[tau] = p;
    }
    __syncthreads();

    // elementwise: rt, kt, b  (4 elems per thread)
    for (int q = tid; q < CC_ * 64; q += 512) {
        int s = q >> 6, i = q & 63;
        float wcs  = wc[s][i];
        float wcs1 = wc[s + 1][i];
        float wcc  = wc[CC_][i];
        float rt_ = sR[s][i] * expf(wcs);
        float kt_ = sK[s][i] * expf(-wcs1);
        float bb  = sK[s][i] * expf(wcc - wcs1);
        sR[s][i] = rt_;
        sW[s][i] = kt_;
        sK[s][i] = bb;
        rt[base + (size_t)s * KD_ + i] = rt_;
    }
    if (tid < 64) Dc[(size_t)bid * 64 + tid] = expf(wc[CC_][tid]);
    __syncthreads();

    // score A[tau][sig]: 2 sigs per thread, K-rotated reads
    {
        int tau = tid >> 4, s0 = (tid & 15) * 2;
        float a0 = 0, a1 = 0;
        for (int i0 = 0; i0 < 64; i0 += 4) {
            int i = (i0 + ((tid & 15) << 2)) & 63;
            float4 rr  = *(const float4*)&sR[tau][i];
            float4 k0v = *(const float4*)&sW[s0 + 0][i];
            float4 k1v = *(const float4*)&sW[s0 + 1][i];
            a0 += rr.x * k0v.x + rr.y * k0v.y + rr.z * k0v.z + rr.w * k0v.w;
            a1 += rr.x * k1v.x + rr.y * k1v.y + rr.z * k1v.z + rr.w * k1v.w;
        }
        sA[tau][s0 + 0] = (s0 + 0 < tau) ? a0 : ((s0 + 0 == tau) ? diag[tau] : 0.f);
        sA[tau][s0 + 1] = (s0 + 1 < tau) ? a1 : ((s0 + 1 == tau) ? diag[tau] : 0.f);
    }
    __syncthreads();

    // o_intra[tau][j] = sum_s A[tau][s] * V[s][j]   (4 floats per thread)
    {
        int tau = tid >> 4, j0 = (tid & 15) * 4;
        float o_[4] __attribute__((aligned(16))) = {};
        for (int s = 0; s < CC_; ++s) {
            float a = sA[tau][s];
            float4 vv = *(const float4*)&sV[s][j0];
            o_[0] += a * vv.x; o_[1] += a * vv.y;
            o_[2] += a * vv.z; o_[3] += a * vv.w;
        }
        size_t ob = base + (size_t)tau * KD_ + j0;
        *(float4*)&ointra[ob] = *(float4*)&o_[0];
    }
    // B[i][j] = sum_s b[s][i] * V[s][j]   (8 floats per thread)
    {
        int i = tid >> 3, j0 = (tid & 7) * 8;
        float bacc[8] __attribute__((aligned(16))) = {};
        for (int s = 0; s < CC_; ++s) {
            float bi = sK[s][i];
            float4 v0 = *(const float4*)&sV[s][j0];
            float4 v1 = *(const float4*)&sV[s][j0 + 4];
            bacc[0] += bi * v0.x; bacc[1] += bi * v0.y;
            bacc[2] += bi * v0.z; bacc[3] += bi * v0.w;
            bacc[4] += bi * v1.x; bacc[5] += bi * v1.y;
            bacc[6] += bi * v1.z; bacc[7] += bi * v1.w;
        }
        size_t bb = ((size_t)bid << 12) + i * 64 + j0;
        *(float4*)&Bc[bb + 0] = *(float4*)&bacc[0];
        *(float4*)&Bc[bb + 4] = *(float4*)&bacc[4];
    }
}

// ---------------------------------------------------------------------------
// Phase B with next-iteration prefetch (hides load latency one step ahead).
__global__ __launch_bounds__(256) void scan_chunkB(float* BS, const float* __restrict__ Dc) {
    int g = blockIdx.x * 256 + threadIdx.x;
    int bh = g >> 12, ij = g & 4095, i = ij >> 6;
    float S = 0.f;
    size_t base = ((size_t)bh << 17) + ij;
    float bv = BS[base];
    float d  = Dc[(size_t)(bh * NC_) * 64 + i];
    for (int c = 0; c < NC_; ++c) {
        size_t idx = base + ((size_t)c << 12);
        float bv2 = 0.f, d2 = 0.f;
        if (c + 1 < NC_) {
            bv2 = BS[idx + 4096];
            d2  = Dc[(size_t)(bh * NC_ + c + 1) * 64 + i];
        }
        BS[idx] = S;
        S = d * S + bv;
        bv = bv2; d = d2;
    }
}

// ---------------------------------------------------------------------------
// Phase C fused with per-head LN + swish gate -> tiled bf16 A-layout.
// 512 threads (8 waves): 16 lanes per output row, 4 cols each.
__global__ __launch_bounds__(512) void scan_chunkC_ln(const float* __restrict__ rt,
                                                      const float* __restrict__ BS,
                                                      const float* __restrict__ oi,
                                                      const float* __restrict__ gb,
                                                      const float* __restrict__ lw,
                                                      const float* __restrict__ lb,
                                                      ushort* __restrict__ outt) {
    __shared__ float sS[64][64];
    __shared__ float sRt[CC_][68];
    int bid = blockIdx.x;
    int bh = bid >> 5, c = bid & (NC_ - 1);
    int b = bh >> 4, h = bh & 15;
    int tid = threadIdx.x;
    size_t sbase = ((size_t)bid) << 12;
    for (int q = tid; q < 1024; q += 512)
        *(float4*)&sS[q >> 4][(q & 15) << 2] = *(const float4*)&BS[sbase + (q << 2)];
    size_t base = ((size_t)(b * T_ + c * CC_)) * KD_ + h * 64;
    {
        int row = tid >> 4, col4 = (tid & 15) << 2;
        *(float4*)&sRt[row][col4] = *(const float4*)&rt[base + (size_t)row * KD_ + col4];
    }
    __syncthreads();
    int tau = tid >> 4, j0 = (tid & 15) * 4;
    size_t obase = base + (size_t)tau * KD_ + j0;
    float acc[4] __attribute__((aligned(16)));
    *(float4*)&acc[0] = *(const float4*)&oi[obase];
    for (int i = 0; i < 64; ++i) {
        float a = sRt[tau][i];
        float4 vv = *(const float4*)&sS[i][j0];
        acc[0] += a * vv.x; acc[1] += a * vv.y;
        acc[2] += a * vv.z; acc[3] += a * vv.w;
    }
    // layernorm over the 16-lane group (row of 64)
    float s = acc[0] + acc[1] + acc[2] + acc[3];
    s += __shfl_xor(s, 1, 64); s += __shfl_xor(s, 2, 64);
    s += __shfl_xor(s, 4, 64); s += __shfl_xor(s, 8, 64);
    float mean = s * (1.f / 64.f);
    float s2 = 0.f;
    #pragma unroll
    for (int q = 0; q < 4; ++q) { float dx = acc[q] - mean; s2 += dx * dx; }
    s2 += __shfl_xor(s2, 1, 64); s2 += __shfl_xor(s2, 2, 64);
    s2 += __shfl_xor(s2, 4, 64); s2 += __shfl_xor(s2, 8, 64);
    float inv = rsqrtf(s2 * (1.f / 64.f) + 1e-5f);
    float4 lwv = *(const float4*)&lw[j0];
    float4 lbv = *(const float4*)&lb[j0];
    float4 gv  = *(const float4*)&gb[obase];
    float lww[4] = {lwv.x, lwv.y, lwv.z, lwv.w};
    float lbb[4] = {lbv.x, lbv.y, lbv.z, lbv.w};
    float gvv[4] = {gv.x, gv.y, gv.z, gv.w};
    ushort o4[4];
    #pragma unroll
    for (int q = 0; q < 4; ++q) {
        float on = (acc[q] - mean) * inv * lww[q] + lbb[q];
        float g = gvv[q];
        o4[q] = bf16r(on * g / (1.f + expf(-g)));
    }
    int mrow = b * T_ + c * CC_ + tau;
    int col  = h * 64 + j0;
    int rb2 = mrow >> 7, kb2 = col >> 5, gg = (col >> 3) & 3;
    *(ushort4*)&outt[(((size_t)(rb2 * 32 + kb2)) << 12) + ((gg << 7) + (mrow & 127)) * 8 + (col & 7)] = *(ushort4*)o4;
}

// ---------------------------------------------------------------------------
extern "C" void kernel_launch(void* const* d_in, const int* in_sizes, int n_in,
                              void* d_out, int out_size, void* d_ws, size_t ws_size,
                              hipStream_t stream) {
    const float* x     = (const float*)d_in[0];
    const float* mu_x  = (const float*)d_in[1];
    const float* Wx1   = (const float*)d_in[2];
    const float* Wx2   = (const float*)d_in[3];
    const float* xbias = (const float*)d_in[4];
    const float* Wr    = (const float*)d_in[5];
    const float* Wk    = (const float*)d_in[6];
    const float* Wv    = (const float*)d_in[7];
    const float* Ww_a  = (const float*)d_in[8];
    const float* Ww_b  = (const float*)d_in[9];
    const float* bw    = (const float*)d_in[10];
    const float* Wg_a  = (const float*)d_in[11];
    const float* Wg_b  = (const float*)d_in[12];
    const float* bg    = (const float*)d_in[13];
    const float* bonus = (const float*)d_in[14];
    const float* ln_w  = (const float*)d_in[15];
    const float* ln_b  = (const float*)d_in[16];
    const float* Wo    = (const float*)d_in[17];
    float* out = (float*)d_out;

    // workspace layout (float units), with overlays (see launch order)
    float* ws   = (float*)d_ws;
    float* xm   = ws;                               // 4M floats: xmt_r|xmt_k; later gt
    float* lr   = xm   + (size_t)M_ * H_;           // lrt | wx2t (bf16 overlays)
    float* hidw = lr   + (size_t)M_ * 320;          // M_*64
    float* hidg = hidw + (size_t)M_ * 64;           // M_*64
    float* rb_  = hidg + (size_t)M_ * 64;           // M_*KD_ ; xm_w spans rb_..kb_
    float* kb_  = rb_  + (size_t)M_ * KD_;
    float* vb_  = kb_  + (size_t)M_ * KD_;          // xm_g spans vb_..db_
    float* db_  = vb_  + (size_t)M_ * KD_;
    float* gb_  = db_  + (size_t)M_ * KD_;          // first 1M floats double as part_g
    float* ob_  = gb_  + (size_t)M_ * KD_;
    float* BS   = ob_  + (size_t)M_ * KD_;          // 4M floats: part_w | xmt_v | scan B/S
    float* Dc   = BS   + (size_t)1024 * 4096;       // 1024*64
    float* wend = Dc + (size_t)1024 * 64;
    // bf16 overlays (ushort units)
    ushort* xmt_r = (ushort*)xm;                            // 8 MB
    ushort* xmt_k = (ushort*)(xm + (size_t)M_ * H_ / 2);    // 8 MB
    ushort* xmt_v = (ushort*)(BS + 1310720);                // 8 MB (past 4MB part_w)
    float*  xm_w  = rb_;                                    // 16 MB fp32
    float*  xm_g  = vb_;                                    // 16 MB fp32
    float*  partw = BS;                                     // 4 MB (step 3 only)
    float*  partg = gb_;                                    // 4 MB (step 3 only)
    ushort* gt    = (ushort*)xm;                            // 4 MB
    ushort* lrt   = (ushort*)lr;                            // 16*5*8192 = 655360 ush
    ushort* wx2t  = lrt + 655360;                           // 5*32*2*2048 = 655360 ush
    ushort* Wx1t  = (ushort*)wend;                          // 2048*320
    ushort* Wrt   = Wx1t + (size_t)H_ * 320;
    ushort* Wkt   = Wrt  + (size_t)H_ * KD_;
    ushort* Wvt   = Wkt  + (size_t)H_ * KD_;
    ushort* Wot   = Wvt  + (size_t)H_ * KD_;                // 1024*2048

    dim3 blk(256);

    // 0+1a. fused preprocessing: mix_mu + ALL weight conversions (one dispatch)
    prep_all<<<6624, blk, 0, stream>>>(x, mu_x, Wx1, Wr, Wk, Wv, Wo, Wx2,
                                       (ushort*)xm, Wx1t, Wrt, Wot, wx2t);

    // 1b. lrt = tanh((x + delta*mu_x) @ Wx1) as bf16 A-tiled per branch [MFMA, BK=64]
    gemm_bf16t_lr<<<dim3(5, M_ / 128), blk, 0, stream>>>((ushort*)xm, Wx1t, lrt);

    // 2. MFMA mus-GEMM + lerp (K=64, branch on z; 2560 blocks)
    musgemm_mfma<<<dim3(H_ / 64, M_ / 128, 5), blk, 0, stream>>>(lrt, wx2t, x, xbias,
                                                                 xmt_r, xm_w, xmt_k, xmt_v, xm_g);

    // 3. LoRA down-projections (split-K z=2) + tanh reduce (z=2)
    gemm_f32_splitk2<<<dim3(8, M_ / 64, 2), blk, 0, stream>>>(xm_w, xm_g, Ww_a, Wg_a,
                                                              partw, partg);
    reduce_tanh2<<<dim3(128, 2), blk, 0, stream>>>(partw, partg, hidw, hidg);

    // 4. LoRA up-projections (z=2): log-decay and raw gate
    gemm_f32_up2<<<dim3(KD_ / 64, M_ / 64, 2), blk, 0, stream>>>(hidw, hidg, Ww_b, Wg_b,
                                                                 bw, bg, db_, gb_);

    // 5. r/k/v projections fused [bf16 MFMA, BK=64], 768 blocks, XCD-swizzled
    gemm_bf16t<0, 3><<<dim3(KD_ / 64, M_ / 128, 3), blk, 0, stream>>>(xmt_r, xmt_k, xmt_v,
                                                                      Wrt, rb_, H_, KD_);

    // 6. chunk-parallel scan; phases A and C at 512 threads (8 waves, 2x TLP)
    scan_chunkA<<<B_ * NH_ * NC_, dim3(512), 0, stream>>>(rb_, kb_, vb_, db_, bonus,
                                                          rb_ /*rt in place*/, ob_, BS, Dc);
    scan_chunkB<<<(B_ * NH_ * 4096) / 256, blk, 0, stream>>>(BS, Dc);
    scan_chunkC_ln<<<B_ * NH_ * NC_, dim3(512), 0, stream>>>(rb_, BS, ob_, gb_, ln_w, ln_b, gt);

    // 7. out = gated @ Wo  [bf16 MFMA, BK=64], 512 blocks, XCD-swizzled
    gemm_bf16t<0, 1><<<dim3(H_ / 64, M_ / 128), blk, 0, stream>>>(gt, nullptr, nullptr,
                                                                  Wot, out, KD_, H_);
}

// Round 24
// 224.132 us; speedup vs baseline: 1.0415x; 1.0173x over previous
//
#include <hip/hip_runtime.h>
#include <hip/hip_bf16.h>

#define H_    2048
#define NH_   16
#define KD_   1024
#define DK_   64
#define T_    1024
#define B_    2
#define M_    (B_*T_)     // 2048 rows
#define RL_   64
#define CC_   32          // scan chunk length
#define NC_   (T_/CC_)    // 32 chunks per sequence

typedef short bf16x8 __attribute__((ext_vector_type(8)));   // 8 bf16 (4 VGPR)
typedef float f32x4  __attribute__((ext_vector_type(4)));   // MFMA acc

__device__ __forceinline__ ushort bf16r(float f) {          // RNE fp32->bf16
    union { float f; unsigned u; } v; v.f = f;
    return (ushort)((v.u + 0x7FFF + ((v.u >> 16) & 1)) >> 16);
}

// async global->LDS, 16B per lane; lds base must be wave-uniform
__device__ __forceinline__ void gl_lds16(const void* g, void* l) {
    __builtin_amdgcn_global_load_lds((const __attribute__((address_space(1))) void*)g,
                                     (__attribute__((address_space(3))) void*)l, 16, 0, 0);
}

// XCD-aware bijective block swizzle (requires nwg % 8 == 0)
__device__ __forceinline__ void xcd_swz(int& bx, int& by, int& bz) {
    int gx = gridDim.x, gy = gridDim.y;
    int nwg = gx * gy * gridDim.z;
    int bid = ((int)blockIdx.z * gy + blockIdx.y) * gx + blockIdx.x;
    int swz = (bid & 7) * (nwg >> 3) + (bid >> 3);
    bx = swz % gx;
    int rem = swz / gx;
    by = rem % gy;
    bz = rem / gy;
}

// ---------------------------------------------------------------------------
// Tiled bf16 layouts:
//  A-tiles (BM=128, BK=32): 4096 bf16/tile, elem (r,k): off = (g*128+r)*8+(k&7), g=(k>>3)&3
//  B-tiles (BN=64, BK=32): 2048 bf16/tile, elem (c,k): off = (g*64+c)*8+(k&7)
// ---------------------------------------------------------------------------

// W [K][N] fp32 -> tiled bf16 B-layout for one (kb, nb) 32x64 block
__device__ __forceinline__ void conv_body(const float* __restrict__ W,
                                          ushort* __restrict__ Wt,
                                          int K, int N, int kb, int nb,
                                          float (*s)[68], int t) {
    #pragma unroll
    for (int i = 0; i < 2; ++i) {
        int q = t + i * 256;
        int k = q >> 4, c4 = (q & 15) << 2;
        *(float4*)&s[k][c4] = *(const float4*)&W[(size_t)(kb * 32 + k) * N + nb * 64 + c4];
    }
    __syncthreads();
    int g = t >> 6, c = t & 63;
    ushort o[8];
    #pragma unroll
    for (int e = 0; e < 8; ++e) o[e] = bf16r(s[g * 8 + e][c]);
    *(uint4*)&Wt[((size_t)(nb * (K >> 5) + kb)) * 2048 + t * 8] = *(uint4*)o;
}

// ---------------------------------------------------------------------------
// Fused preprocessing: mix_mu (xx -> bf16 A-tiled) + all weight conversions.
// Block ranges: [0,2048) mix | [2048,2368) Wx1 | [2368,5440) r/k/v |
//               [5440,6464) Wo | [6464,6624) Wx2
__global__ __launch_bounds__(256) void prep_all(const float* __restrict__ x,
                                                const float* __restrict__ mu,
                                                const float* __restrict__ Wx1,
                                                const float* __restrict__ W0,
                                                const float* __restrict__ W1,
                                                const float* __restrict__ W2,
                                                const float* __restrict__ Wo,
                                                const float* __restrict__ Wx2,
                                                ushort* __restrict__ At,
                                                ushort* __restrict__ Wx1t,
                                                ushort* __restrict__ Wrt,
                                                ushort* __restrict__ Wot,
                                                ushort* __restrict__ wx2t) {
    __shared__ float s[64][68];
    int bid = blockIdx.x;
    int tid = threadIdx.x;
    if (bid < 2048) {                      // ---- mix_mu ----
        int c = bid * 256 + tid;
        int bt = c >> 8, k8 = c & 255;
        int k = k8 << 3;
        int t = bt & (T_ - 1);
        const float* xp = &x[(size_t)bt * H_ + k];
        float4 xa = *(const float4*)xp;
        float4 xb = *(const float4*)(xp + 4);
        float4 sa = make_float4(0,0,0,0), sb = make_float4(0,0,0,0);
        if (t > 0) { sa = *(const float4*)(xp - H_); sb = *(const float4*)(xp - H_ + 4); }
        float4 ma = *(const float4*)&mu[k];
        float4 mb = *(const float4*)&mu[k + 4];
        ushort o[8];
        o[0] = bf16r(xa.x + (sa.x - xa.x) * ma.x);
        o[1] = bf16r(xa.y + (sa.y - xa.y) * ma.y);
        o[2] = bf16r(xa.z + (sa.z - xa.z) * ma.z);
        o[3] = bf16r(xa.w + (sa.w - xa.w) * ma.w);
        o[4] = bf16r(xb.x + (sb.x - xb.x) * mb.x);
        o[5] = bf16r(xb.y + (sb.y - xb.y) * mb.y);
        o[6] = bf16r(xb.z + (sb.z - xb.z) * mb.z);
        o[7] = bf16r(xb.w + (sb.w - xb.w) * mb.w);
        int rb = bt >> 7, kb = k8 >> 2, g = k8 & 3, r = bt & 127;
        *(uint4*)&At[(((size_t)(rb * 64 + kb)) << 12) + ((g << 7) + r) * 8] = *(uint4*)o;
        return;
    }
    bid -= 2048;
    if (bid < 320) {                       // ---- convert Wx1 [2048][320] ----
        conv_body(Wx1, Wx1t, H_, 320, bid / 5, bid % 5, s, tid);
        return;
    }
    bid -= 320;
    if (bid < 3072) {                      // ---- convert Wr/Wk/Wv ----
        int nb = bid & 15, kb = (bid >> 4) & 63, z = bid >> 10;
        const float* W = (z == 0) ? W0 : (z == 1) ? W1 : W2;
        conv_body(W, Wrt + (size_t)z * ((size_t)H_ * KD_), H_, KD_, kb, nb, s, tid);
        return;
    }
    bid -= 3072;
    if (bid < 1024) {                      // ---- convert Wo [1024][2048] ----
        conv_body(Wo, Wot, KD_, H_, bid >> 5, bid & 31, s, tid);
        return;
    }
    bid -= 1024;
    {                                      // ---- convert Wx2 per-branch ----
        int nb = bid & 31, z = bid >> 5;
        for (int q = tid; q < 1024; q += 256) {
            int row = q >> 4, c4 = (q & 15) << 2;
            *(float4*)&s[row][c4] = *(const float4*)&Wx2[(size_t)(nb * 64 + row) * 320 + z * 64 + c4];
        }
        __syncthreads();
        for (int q = tid; q < 512; q += 256) {
            int kb = q >> 8, i = q & 255;
            int g = i >> 6, c = i & 63;
            ushort o[8];
            #pragma unroll
            for (int e = 0; e < 8; ++e) o[e] = bf16r(s[c][kb * 32 + g * 8 + e]);
            *(uint4*)&wx2t[(((size_t)(z * 32 + nb)) * 2 + kb) * 2048 + i * 8] = *(uint4*)o;
        }
    }
}

// ---------------------------------------------------------------------------
// bf16 MFMA GEMM, BM=128 x BN=64, BK=64 (two 32-K subtiles per iteration).
// Double-buffered global_load_lds staging, XCD-swizzled grid (Wo GEMM).
// EPI: 0 = none, 1 = tanh
template<int EPI>
__global__ __launch_bounds__(256) void gemm_bf16t(const ushort* __restrict__ At,
                                                  const ushort* __restrict__ Bt,
                                                  float* __restrict__ C,
                                                  int K, int ldc) {
    __shared__ ushort Alds[2][8192];
    __shared__ ushort Blds[2][4096];
    int bx, by, bz;
    xcd_swz(bx, by, bz);
    (void)bz;
    int tid = threadIdx.x;
    int w = tid >> 6, l = tid & 63;
    int KB32 = K >> 5;
    int KB64 = K >> 6;
    const ushort* Ag = At + (size_t)by * KB32 * 4096 + tid * 8;
    const ushort* Bg = Bt + (size_t)bx * KB32 * 2048 + tid * 8;
    int wr = (w >> 1) << 6, wc = (w & 1) << 5;
    int a_off = (((l >> 4) << 7) + wr + (l & 15)) << 3;
    int b_off = (((l >> 4) << 6) + wc + (l & 15)) << 3;
    f32x4 acc[8] = {};
    #pragma unroll
    for (int j = 0; j < 4; ++j) gl_lds16(Ag + j * 2048, &Alds[0][w * 512 + j * 2048]);
    #pragma unroll
    for (int j = 0; j < 2; ++j) gl_lds16(Bg + j * 2048, &Blds[0][w * 512 + j * 2048]);
    __syncthreads();
    for (int kt = 0; kt < KB64; ++kt) {
        int cur = kt & 1;
        if (kt + 1 < KB64) {
            Ag += 8192; Bg += 4096;
            int nxt = cur ^ 1;
            #pragma unroll
            for (int j = 0; j < 4; ++j) gl_lds16(Ag + j * 2048, &Alds[nxt][w * 512 + j * 2048]);
            #pragma unroll
            for (int j = 0; j < 2; ++j) gl_lds16(Bg + j * 2048, &Blds[nxt][w * 512 + j * 2048]);
        }
        #pragma unroll
        for (int kb2 = 0; kb2 < 2; ++kb2) {
            const ushort* Ab = &Alds[cur][kb2 * 4096 + a_off];
            const ushort* Bb = &Blds[cur][kb2 * 2048 + b_off];
            bf16x8 af0 = *(const bf16x8*)(Ab);
            bf16x8 af1 = *(const bf16x8*)(Ab + 128);
            bf16x8 af2 = *(const bf16x8*)(Ab + 256);
            bf16x8 af3 = *(const bf16x8*)(Ab + 384);
            bf16x8 bf0 = *(const bf16x8*)(Bb);
            bf16x8 bf1 = *(const bf16x8*)(Bb + 128);
            acc[0] = __builtin_amdgcn_mfma_f32_16x16x32_bf16(af0, bf0, acc[0], 0, 0, 0);
            acc[1] = __builtin_amdgcn_mfma_f32_16x16x32_bf16(af0, bf1, acc[1], 0, 0, 0);
            acc[2] = __builtin_amdgcn_mfma_f32_16x16x32_bf16(af1, bf0, acc[2], 0, 0, 0);
            acc[3] = __builtin_amdgcn_mfma_f32_16x16x32_bf16(af1, bf1, acc[3], 0, 0, 0);
            acc[4] = __builtin_amdgcn_mfma_f32_16x16x32_bf16(af2, bf0, acc[4], 0, 0, 0);
            acc[5] = __builtin_amdgcn_mfma_f32_16x16x32_bf16(af2, bf1, acc[5], 0, 0, 0);
            acc[6] = __builtin_amdgcn_mfma_f32_16x16x32_bf16(af3, bf0, acc[6], 0, 0, 0);
            acc[7] = __builtin_amdgcn_mfma_f32_16x16x32_bf16(af3, bf1, acc[7], 0, 0, 0);
        }
        __syncthreads();
    }
    int row0 = (by << 7) + wr + ((l >> 4) << 2);
    int col0 = (bx << 6) + wc + (l & 15);
    #pragma unroll
    for (int fr = 0; fr < 4; ++fr)
        #pragma unroll
        for (int fc = 0; fc < 2; ++fc) {
            f32x4 v = acc[fr * 2 + fc];
            #pragma unroll
            for (int q = 0; q < 4; ++q) {
                float o = v[q];
                if (EPI == 1) o = tanhf(o);
                C[(size_t)(row0 + fr * 16 + q) * ldc + col0 + fc * 16] = o;
            }
        }
}

// ---------------------------------------------------------------------------
// MERGED: r/k/v MFMA GEMM (768 blocks, XCD-swizzled over its range) +
// LoRA split-K down-projections (512 blocks). Both depend only on musgemm.
// NOTE: xm_w / xm_g MUST NOT alias the rkv output (rb_/kb_/vb_) — they live
// in dedicated workspace regions (R22 failure was exactly this alias).
__global__ __launch_bounds__(256) void gemm_rkv_splitk(const ushort* __restrict__ A0,
                                                       const ushort* __restrict__ A1,
                                                       const ushort* __restrict__ A2,
                                                       const ushort* __restrict__ Bt0,
                                                       float* __restrict__ C0,
                                                       const float* __restrict__ Aw,
                                                       const float* __restrict__ Ag2,
                                                       const float* __restrict__ Wwa,
                                                       const float* __restrict__ Wga,
                                                       float* __restrict__ partw,
                                                       float* __restrict__ partg) {
    __shared__ ushort smem[24576];         // 48 KB arena
    int p = blockIdx.x;
    int tid = threadIdx.x;
    if (p < 768) {
        // ---- r/k/v bf16 MFMA GEMM, K=2048, BK=64, swizzled over 768 ----
        ushort (*Alds)[8192] = (ushort(*)[8192])smem;            // 2 x 16 KB
        ushort (*Blds)[4096] = (ushort(*)[4096])(smem + 16384);  // 2 x 8 KB
        int swz = (p & 7) * 96 + (p >> 3);        // bijective, nwg=768
        int bx = swz & 15;
        int rem = swz >> 4;
        int by = rem & 15;
        int bz = rem >> 4;                        // 0..2 branch
        int w = tid >> 6, l = tid & 63;
        const int KB32 = H_ >> 5, KB64 = H_ >> 6;
        const ushort* At = (bz == 0) ? A0 : (bz == 1) ? A1 : A2;
        const ushort* Bt = Bt0 + (size_t)bz * ((size_t)H_ * KD_);
        float* C = C0 + (size_t)bz * ((size_t)M_ * KD_);
        const ushort* Ag = At + (size_t)by * KB32 * 4096 + tid * 8;
        const ushort* Bg = Bt + (size_t)bx * KB32 * 2048 + tid * 8;
        int wr = (w >> 1) << 6, wc = (w & 1) << 5;
        int a_off = (((l >> 4) << 7) + wr + (l & 15)) << 3;
        int b_off = (((l >> 4) << 6) + wc + (l & 15)) << 3;
        f32x4 acc[8] = {};
        #pragma unroll
        for (int j = 0; j < 4; ++j) gl_lds16(Ag + j * 2048, &Alds[0][w * 512 + j * 2048]);
        #pragma unroll
        for (int j = 0; j < 2; ++j) gl_lds16(Bg + j * 2048, &Blds[0][w * 512 + j * 2048]);
        __syncthreads();
        for (int kt = 0; kt < KB64; ++kt) {
            int cur = kt & 1;
            if (kt + 1 < KB64) {
                Ag += 8192; Bg += 4096;
                int nxt = cur ^ 1;
                #pragma unroll
                for (int j = 0; j < 4; ++j) gl_lds16(Ag + j * 2048, &Alds[nxt][w * 512 + j * 2048]);
                #pragma unroll
                for (int j = 0; j < 2; ++j) gl_lds16(Bg + j * 2048, &Blds[nxt][w * 512 + j * 2048]);
            }
            #pragma unroll
            for (int kb2 = 0; kb2 < 2; ++kb2) {
                const ushort* Ab = &Alds[cur][kb2 * 4096 + a_off];
                const ushort* Bb = &Blds[cur][kb2 * 2048 + b_off];
                bf16x8 af0 = *(const bf16x8*)(Ab);
                bf16x8 af1 = *(const bf16x8*)(Ab + 128);
                bf16x8 af2 = *(const bf16x8*)(Ab + 256);
                bf16x8 af3 = *(const bf16x8*)(Ab + 384);
                bf16x8 bf0 = *(const bf16x8*)(Bb);
                bf16x8 bf1 = *(const bf16x8*)(Bb + 128);
                acc[0] = __builtin_amdgcn_mfma_f32_16x16x32_bf16(af0, bf0, acc[0], 0, 0, 0);
                acc[1] = __builtin_amdgcn_mfma_f32_16x16x32_bf16(af0, bf1, acc[1], 0, 0, 0);
                acc[2] = __builtin_amdgcn_mfma_f32_16x16x32_bf16(af1, bf0, acc[2], 0, 0, 0);
                acc[3] = __builtin_amdgcn_mfma_f32_16x16x32_bf16(af1, bf1, acc[3], 0, 0, 0);
                acc[4] = __builtin_amdgcn_mfma_f32_16x16x32_bf16(af2, bf0, acc[4], 0, 0, 0);
                acc[5] = __builtin_amdgcn_mfma_f32_16x16x32_bf16(af2, bf1, acc[5], 0, 0, 0);
                acc[6] = __builtin_amdgcn_mfma_f32_16x16x32_bf16(af3, bf0, acc[6], 0, 0, 0);
                acc[7] = __builtin_amdgcn_mfma_f32_16x16x32_bf16(af3, bf1, acc[7], 0, 0, 0);
            }
            __syncthreads();
        }
        int row0 = (by << 7) + wr + ((l >> 4) << 2);
        int col0 = (bx << 6) + wc + (l & 15);
        #pragma unroll
        for (int fr = 0; fr < 4; ++fr)
            #pragma unroll
            for (int fc = 0; fc < 2; ++fc) {
                f32x4 v = acc[fr * 2 + fc];
                #pragma unroll
                for (int q = 0; q < 4; ++q)
                    C[(size_t)(row0 + fr * 16 + q) * KD_ + col0 + fc * 16] = v[q];
            }
        return;
    }
    // ---- LoRA split-K down-proj: p768 in [0,512) = (kc 8, row 32, z 2) ----
    {
        int p768 = p - 768;
        int kc = p768 & 7, ry = (p768 >> 3) & 31, z = p768 >> 8;
        float (*As)[68] = (float(*)[68])smem;                    // 16x68 f
        float (*Bs)[68] = (float(*)[68])(smem + 2176);           // 16x68 f (byte off 4352)
        const float* A = z ? Ag2 : Aw;
        const float* W = z ? Wga : Wwa;
        float* part = z ? partg : partw;
        int tx = tid & 15, ty = tid >> 4;
        int row0 = ry * 64;
        int kbase = kc * 256;
        int am = tid >> 2, ak = (tid & 3) << 2;
        int bk = tid >> 4, bn = (tid & 15) << 2;
        float acc[4][4] = {};
        float4 av = *(const float4*)&A[(size_t)(row0 + am) * H_ + kbase + ak];
        float4 bv = *(const float4*)&W[(size_t)(kbase + bk) * 64 + bn];
        for (int k0 = 0; k0 < 256; k0 += 16) {
            __syncthreads();
            As[ak + 0][am] = av.x; As[ak + 1][am] = av.y;
            As[ak + 2][am] = av.z; As[ak + 3][am] = av.w;
            *(float4*)&Bs[bk][bn] = bv;
            __syncthreads();
            if (k0 + 16 < 256) {
                av = *(const float4*)&A[(size_t)(row0 + am) * H_ + kbase + k0 + 16 + ak];
                bv = *(const float4*)&W[(size_t)(kbase + k0 + 16 + bk) * 64 + bn];
            }
            #pragma unroll
            for (int kk = 0; kk < 16; ++kk) {
                float4 a = *(const float4*)&As[kk][ty << 2];
                float4 b = *(const float4*)&Bs[kk][tx << 2];
                float aa[4] = {a.x, a.y, a.z, a.w};
                float bb[4] = {b.x, b.y, b.z, b.w};
                #pragma unroll
                for (int i = 0; i < 4; ++i)
                    #pragma unroll
                    for (int j = 0; j < 4; ++j)
                        acc[i][j] = fmaf(aa[i], bb[j], acc[i][j]);
            }
        }
        float* pc = part + (size_t)kc * (M_ * 64);
        #pragma unroll
        for (int i = 0; i < 4; ++i) {
            int r = row0 + (ty << 2) + i;
            #pragma unroll
            for (int j = 0; j < 4; ++j)
                pc[(size_t)r * 64 + (tx << 2) + j] = acc[i][j];
        }
    }
}

// ---------------------------------------------------------------------------
// Wx1 GEMM variant: K=2048, BK=64, grid (branch=5, rb=16), XCD-swizzled;
// epilogue writes lr = tanh(acc) as bf16 A-fragment-tiled lrt (K=64/branch).
__global__ __launch_bounds__(256) void gemm_bf16t_lr(const ushort* __restrict__ At,
                                                     const ushort* __restrict__ Bt,
                                                     ushort* __restrict__ lrt) {
    __shared__ ushort Alds[2][8192];
    __shared__ ushort Blds[2][4096];
    int bx, by, bz;
    xcd_swz(bx, by, bz);
    (void)bz;
    int tid = threadIdx.x;
    int w = tid >> 6, l = tid & 63;
    const int KB32 = H_ >> 5;   // 64 tiles
    const int KB64 = H_ >> 6;   // 32 iterations
    const ushort* Ag = At + (size_t)by * KB32 * 4096 + tid * 8;
    const ushort* Bg = Bt + (size_t)bx * KB32 * 2048 + tid * 8;
    int wr = (w >> 1) << 6, wc = (w & 1) << 5;
    int a_off = (((l >> 4) << 7) + wr + (l & 15)) << 3;
    int b_off = (((l >> 4) << 6) + wc + (l & 15)) << 3;
    f32x4 acc[8] = {};
    #pragma unroll
    for (int j = 0; j < 4; ++j) gl_lds16(Ag + j * 2048, &Alds[0][w * 512 + j * 2048]);
    #pragma unroll
    for (int j = 0; j < 2; ++j) gl_lds16(Bg + j * 2048, &Blds[0][w * 512 + j * 2048]);
    __syncthreads();
    for (int kt = 0; kt < KB64; ++kt) {
        int cur = kt & 1;
        if (kt + 1 < KB64) {
            Ag += 8192; Bg += 4096;
            int nxt = cur ^ 1;
            #pragma unroll
            for (int j = 0; j < 4; ++j) gl_lds16(Ag + j * 2048, &Alds[nxt][w * 512 + j * 2048]);
            #pragma unroll
            for (int j = 0; j < 2; ++j) gl_lds16(Bg + j * 2048, &Blds[nxt][w * 512 + j * 2048]);
        }
        #pragma unroll
        for (int kb2 = 0; kb2 < 2; ++kb2) {
            const ushort* Ab = &Alds[cur][kb2 * 4096 + a_off];
            const ushort* Bb = &Blds[cur][kb2 * 2048 + b_off];
            bf16x8 af0 = *(const bf16x8*)(Ab);
            bf16x8 af1 = *(const bf16x8*)(Ab + 128);
            bf16x8 af2 = *(const bf16x8*)(Ab + 256);
            bf16x8 af3 = *(const bf16x8*)(Ab + 384);
            bf16x8 bf0 = *(const bf16x8*)(Bb);
            bf16x8 bf1 = *(const bf16x8*)(Bb + 128);
            acc[0] = __builtin_amdgcn_mfma_f32_16x16x32_bf16(af0, bf0, acc[0], 0, 0, 0);
            acc[1] = __builtin_amdgcn_mfma_f32_16x16x32_bf16(af0, bf1, acc[1], 0, 0, 0);
            acc[2] = __builtin_amdgcn_mfma_f32_16x16x32_bf16(af1, bf0, acc[2], 0, 0, 0);
            acc[3] = __builtin_amdgcn_mfma_f32_16x16x32_bf16(af1, bf1, acc[3], 0, 0, 0);
            acc[4] = __builtin_amdgcn_mfma_f32_16x16x32_bf16(af2, bf0, acc[4], 0, 0, 0);
            acc[5] = __builtin_amdgcn_mfma_f32_16x16x32_bf16(af2, bf1, acc[5], 0, 0, 0);
            acc[6] = __builtin_amdgcn_mfma_f32_16x16x32_bf16(af3, bf0, acc[6], 0, 0, 0);
            acc[7] = __builtin_amdgcn_mfma_f32_16x16x32_bf16(af3, bf1, acc[7], 0, 0, 0);
        }
        __syncthreads();
    }
    int rloc0 = wr + ((l >> 4) << 2);              // local row in [0,128)
    size_t tbase = ((size_t)(by * 5 + bx)) * 8192;
    #pragma unroll
    for (int fr = 0; fr < 4; ++fr)
        #pragma unroll
        for (int fc = 0; fc < 2; ++fc) {
            f32x4 v = acc[fr * 2 + fc];
            int c = wc + fc * 16 + (l & 15);       // branch-local K index [0,64)
            int kb2 = c >> 5, g = (c >> 3) & 3, e = c & 7;
            #pragma unroll
            for (int q = 0; q < 4; ++q) {
                int r = rloc0 + fr * 16 + q;
                lrt[tbase + (size_t)kb2 * 4096 + ((g << 7) + r) * 8 + e] = bf16r(tanhf(v[q]));
            }
        }
}

// ---------------------------------------------------------------------------
// MFMA mus-GEMM + lerp: C = lrt @ Wx2t (K=64) per branch z; epilogue applies
// bias + lerp vs x/shift and writes branch-specific outputs.
__global__ __launch_bounds__(256) void musgemm_mfma(const ushort* __restrict__ lrt,
                                                    const ushort* __restrict__ wx2t,
                                                    const float* __restrict__ x,
                                                    const float* __restrict__ xbias,
                                                    ushort* __restrict__ xmt_r,
                                                    float*  __restrict__ xm_w,
                                                    ushort* __restrict__ xmt_k,
                                                    ushort* __restrict__ xmt_v,
                                                    float*  __restrict__ xm_g) {
    __shared__ ushort Alds[8192];
    __shared__ ushort Blds[4096];
    int tid = threadIdx.x;
    int w = tid >> 6, l = tid & 63;
    int z = blockIdx.z;
    const ushort* Ag = lrt + ((size_t)(blockIdx.y * 5 + z)) * 8192 + tid * 8;
    const ushort* Bg = wx2t + ((size_t)(z * 32 + blockIdx.x)) * 4096 + tid * 8;
    gl_lds16(Ag,        &Alds[w * 512]);
    gl_lds16(Ag + 2048, &Alds[w * 512 + 2048]);
    gl_lds16(Ag + 4096, &Alds[w * 512 + 4096]);
    gl_lds16(Ag + 6144, &Alds[w * 512 + 6144]);
    gl_lds16(Bg,        &Blds[w * 512]);
    gl_lds16(Bg + 2048, &Blds[w * 512 + 2048]);
    int wr = (w >> 1) << 6, wc = (w & 1) << 5;
    int a_off = (((l >> 4) << 7) + wr + (l & 15)) << 3;
    int b_off = (((l >> 4) << 6) + wc + (l & 15)) << 3;
    f32x4 acc[8] = {};
    __syncthreads();
    #pragma unroll
    for (int kb = 0; kb < 2; ++kb) {
        const ushort* Ab = &Alds[kb * 4096 + a_off];
        const ushort* Bb = &Blds[kb * 2048 + b_off];
        bf16x8 af0 = *(const bf16x8*)(Ab);
        bf16x8 af1 = *(const bf16x8*)(Ab + 128);
        bf16x8 af2 = *(const bf16x8*)(Ab + 256);
        bf16x8 af3 = *(const bf16x8*)(Ab + 384);
        bf16x8 bf0 = *(const bf16x8*)(Bb);
        bf16x8 bf1 = *(const bf16x8*)(Bb + 128);
        acc[0] = __builtin_amdgcn_mfma_f32_16x16x32_bf16(af0, bf0, acc[0], 0, 0, 0);
        acc[1] = __builtin_amdgcn_mfma_f32_16x16x32_bf16(af0, bf1, acc[1], 0, 0, 0);
        acc[2] = __builtin_amdgcn_mfma_f32_16x16x32_bf16(af1, bf0, acc[2], 0, 0, 0);
        acc[3] = __builtin_amdgcn_mfma_f32_16x16x32_bf16(af1, bf1, acc[3], 0, 0, 0);
        acc[4] = __builtin_amdgcn_mfma_f32_16x16x32_bf16(af2, bf0, acc[4], 0, 0, 0);
        acc[5] = __builtin_amdgcn_mfma_f32_16x16x32_bf16(af2, bf1, acc[5], 0, 0, 0);
        acc[6] = __builtin_amdgcn_mfma_f32_16x16x32_bf16(af3, bf0, acc[6], 0, 0, 0);
        acc[7] = __builtin_amdgcn_mfma_f32_16x16x32_bf16(af3, bf1, acc[7], 0, 0, 0);
    }
    int row0 = (blockIdx.y << 7) + wr + ((l >> 4) << 2);
    int col0 = (blockIdx.x << 6) + wc + (l & 15);
    #pragma unroll
    for (int fr = 0; fr < 4; ++fr)
        #pragma unroll
        for (int fc = 0; fc < 2; ++fc) {
            f32x4 v = acc[fr * 2 + fc];
            int h = col0 + fc * 16;
            float bias = xbias[z * H_ + h];
            #pragma unroll
            for (int q = 0; q < 4; ++q) {
                int r = row0 + fr * 16 + q;
                int t = r & (T_ - 1);
                const float* xp = &x[(size_t)r * H_ + h];
                float xv = *xp;
                float sh = (t > 0) ? *(xp - H_) : 0.f;
                float o = xv + (sh - xv) * (v[q] + bias);
                if (z == 0 || z == 2 || z == 3) {
                    ushort* dst = (z == 0) ? xmt_r : (z == 2) ? xmt_k : xmt_v;
                    int rb = r >> 7, kb = h >> 5, g = (h >> 3) & 3;
                    dst[(((size_t)(rb * 64 + kb)) << 12) + ((g << 7) + (r & 127)) * 8 + (h & 7)] = bf16r(o);
                } else {
                    float* dst = (z == 1) ? xm_w : xm_g;
                    dst[(size_t)r * H_ + h] = o;
                }
            }
        }
}

// ---------------------------------------------------------------------------
// Fused LoRA up-projections (z=0: decay path, z=1: gate path), K=64.
__global__ __launch_bounds__(256) void gemm_f32_up2(const float* __restrict__ hidw,
                                                    const float* __restrict__ hidg,
                                                    const float* __restrict__ Wwb,
                                                    const float* __restrict__ Wgb,
                                                    const float* __restrict__ bw,
                                                    const float* __restrict__ bg,
                                                    float* __restrict__ db,
                                                    float* __restrict__ gb) {
    __shared__ float As[16][68];
    __shared__ float Bs[16][68];
    int z = blockIdx.z;
    const float* A = z ? hidg : hidw;
    const float* W = z ? Wgb : Wwb;
    const float* bias = z ? bg : bw;
    float* C = z ? gb : db;
    int tid = threadIdx.x;
    int tx = tid & 15, ty = tid >> 4;
    int row0 = blockIdx.y * 64, col0 = blockIdx.x * 64;
    int am = tid >> 2, ak = (tid & 3) << 2;
    int bk = tid >> 4, bn = (tid & 15) << 2;
    float acc[4][4] = {};
    float4 av = *(const float4*)&A[(size_t)(row0 + am) * 64 + ak];
    float4 bv = *(const float4*)&W[(size_t)bk * KD_ + col0 + bn];
    for (int k0 = 0; k0 < 64; k0 += 16) {
        __syncthreads();
        As[ak + 0][am] = av.x; As[ak + 1][am] = av.y;
        As[ak + 2][am] = av.z; As[ak + 3][am] = av.w;
        *(float4*)&Bs[bk][bn] = bv;
        __syncthreads();
        if (k0 + 16 < 64) {
            av = *(const float4*)&A[(size_t)(row0 + am) * 64 + k0 + 16 + ak];
            bv = *(const float4*)&W[(size_t)(k0 + 16 + bk) * KD_ + col0 + bn];
        }
        #pragma unroll
        for (int kk = 0; kk < 16; ++kk) {
            float4 a = *(const float4*)&As[kk][ty << 2];
            float4 b = *(const float4*)&Bs[kk][tx << 2];
            float aa[4] = {a.x, a.y, a.z, a.w};
            float bb[4] = {b.x, b.y, b.z, b.w};
            #pragma unroll
            for (int i = 0; i < 4; ++i)
                #pragma unroll
                for (int j = 0; j < 4; ++j)
                    acc[i][j] = fmaf(aa[i], bb[j], acc[i][j]);
        }
    }
    #pragma unroll
    for (int i = 0; i < 4; ++i) {
        int r = row0 + (ty << 2) + i;
        #pragma unroll
        for (int j = 0; j < 4; ++j) {
            int c = col0 + (tx << 2) + j;
            float v = acc[i][j] + bias[c];
            if (z == 0) v = -expf(v);      // store LOG decay
            C[(size_t)r * KD_ + c] = v;
        }
    }
}

// hid = tanh(sum_kc part[kc]) for both paths (grid y selects)
__global__ __launch_bounds__(256) void reduce_tanh2(const float* __restrict__ partw,
                                                    const float* __restrict__ partg,
                                                    float* __restrict__ hidw,
                                                    float* __restrict__ hidg) {
    int z = blockIdx.y;
    const float4* p = (const float4*)(z ? partg : partw);
    float* hid = z ? hidg : hidw;
    int i = blockIdx.x * 256 + threadIdx.x;       // 32768 float4s
    float4 s = p[i];
    #pragma unroll
    for (int kc = 1; kc < 8; ++kc) {
        float4 v = p[i + kc * 32768];
        s.x += v.x; s.y += v.y; s.z += v.z; s.w += v.w;
    }
    s.x = tanhf(s.x); s.y = tanhf(s.y); s.z = tanhf(s.z); s.w = tanhf(s.w);
    ((float4*)hid)[i] = s;
}

// ---------------------------------------------------------------------------
// Chunked scan, phase A — 512 threads (8 waves) per block for 2x latency hiding.
__global__ __launch_bounds__(512) void scan_chunkA(const float* r, const float* k,
                                                   const float* v, const float* ld,
                                                   const float* u,
                                                   float* rt, float* ointra,
                                                   float* Bc, float* Dc) {
    __shared__ float sR[CC_][68], sK[CC_][68], sV[CC_][68], sW[CC_][68];
    __shared__ float wc[CC_ + 1][64];
    __shared__ float sA[CC_][36];
    __shared__ float diag[CC_];
    __shared__ float sU[64];
    int bid = blockIdx.x;
    int bh = bid >> 5, c = bid & (NC_ - 1);
    int b = bh >> 4, h = bh & 15;
    int tid = threadIdx.x;
    size_t base = ((size_t)(b * T_ + c * CC_)) * KD_ + h * 64;

    // staging: 512 float4 slots per array, one per thread
    {
        int row = tid >> 4, col4 = (tid & 15) << 2;
        size_t gi = base + (size_t)row * KD_ + col4;
        *(float4*)&sR[row][col4] = *(const float4*)&r[gi];
        *(float4*)&sK[row][col4] = *(const float4*)&k[gi];
        *(float4*)&sV[row][col4] = *(const float4*)&v[gi];
        *(float4*)&sW[row][col4] = *(const float4*)&ld[gi];
    }
    if (tid < 64) sU[tid] = u[h * 64 + tid];
    __syncthreads();

    // prefix sum of log-decay per dk column (tid<64)
    if (tid < 64) {
        float acc = 0.f;
        wc[0][tid] = 0.f;
        #pragma unroll
        for (int s = 0; s < CC_; ++s) { acc += sW[s][tid]; wc[s + 1][tid] = acc; }
    }
    // diag[tau] = sum_i r*u*k : 16 lanes per tau, 4 elems each
    {
        int tau = tid >> 4, g = tid & 15;
        float p = 0.f;
        #pragma unroll
        for (int q = 0; q < 4; ++q) {
            int i = g * 4 + q;
            p += sR[tau][i] * sU[i] * sK[tau][i];
        }
        p += __shfl_xor(p, 1, 64); p += __shfl_xor(p, 2, 64);
        p += __shfl_xor(p, 4, 64); p += __shfl_xor(p, 8, 64);
        if (g == 0) diag[tau] = p;
    }
    __syncthreads();

    // elementwise: rt, kt, b  (4 elems per thread)
    for (int q = tid; q < CC_ * 64; q += 512) {
        int s = q >> 6, i = q & 63;
        float wcs  = wc[s][i];
        float wcs1 = wc[s + 1][i];
        float wcc  = wc[CC_][i];
        float rt_ = sR[s][i] * expf(wcs);
        float kt_ = sK[s][i] * expf(-wcs1);
        float bb  = sK[s][i] * expf(wcc - wcs1);
        sR[s][i] = rt_;
        sW[s][i] = kt_;
        sK[s][i] = bb;
        rt[base + (size_t)s * KD_ + i] = rt_;
    }
    if (tid < 64) Dc[(size_t)bid * 64 + tid] = expf(wc[CC_][tid]);
    __syncthreads();

    // score A[tau][sig]: 2 sigs per thread, K-rotated reads
    {
        int tau = tid >> 4, s0 = (tid & 15) * 2;
        float a0 = 0, a1 = 0;
        for (int i0 = 0; i0 < 64; i0 += 4) {
            int i = (i0 + ((tid & 15) << 2)) & 63;
            float4 rr  = *(const float4*)&sR[tau][i];
            float4 k0v = *(const float4*)&sW[s0 + 0][i];
            float4 k1v = *(const float4*)&sW[s0 + 1][i];
            a0 += rr.x * k0v.x + rr.y * k0v.y + rr.z * k0v.z + rr.w * k0v.w;
            a1 += rr.x * k1v.x + rr.y * k1v.y + rr.z * k1v.z + rr.w * k1v.w;
        }
        sA[tau][s0 + 0] = (s0 + 0 < tau) ? a0 : ((s0 + 0 == tau) ? diag[tau] : 0.f);
        sA[tau][s0 + 1] = (s0 + 1 < tau) ? a1 : ((s0 + 1 == tau) ? diag[tau] : 0.f);
    }
    __syncthreads();

    // o_intra[tau][j] = sum_s A[tau][s] * V[s][j]   (4 floats per thread)
    {
        int tau = tid >> 4, j0 = (tid & 15) * 4;
        float o_[4] __attribute__((aligned(16))) = {};
        for (int s = 0; s < CC_; ++s) {
            float a = sA[tau][s];
            float4 vv = *(const float4*)&sV[s][j0];
            o_[0] += a * vv.x; o_[1] += a * vv.y;
            o_[2] += a * vv.z; o_[3] += a * vv.w;
        }
        size_t ob = base + (size_t)tau * KD_ + j0;
        *(float4*)&ointra[ob] = *(float4*)&o_[0];
    }
    // B[i][j] = sum_s b[s][i] * V[s][j]   (8 floats per thread)
    {
        int i = tid >> 3, j0 = (tid & 7) * 8;
        float bacc[8] __attribute__((aligned(16))) = {};
        for (int s = 0; s < CC_; ++s) {
            float bi = sK[s][i];
            float4 v0 = *(const float4*)&sV[s][j0];
            float4 v1 = *(const float4*)&sV[s][j0 + 4];
            bacc[0] += bi * v0.x; bacc[1] += bi * v0.y;
            bacc[2] += bi * v0.z; bacc[3] += bi * v0.w;
            bacc[4] += bi * v1.x; bacc[5] += bi * v1.y;
            bacc[6] += bi * v1.z; bacc[7] += bi * v1.w;
        }
        size_t bb = ((size_t)bid << 12) + i * 64 + j0;
        *(float4*)&Bc[bb + 0] = *(float4*)&bacc[0];
        *(float4*)&Bc[bb + 4] = *(float4*)&bacc[4];
    }
}

// ---------------------------------------------------------------------------
// Phase B with next-iteration prefetch (hides load latency one step ahead).
__global__ __launch_bounds__(256) void scan_chunkB(float* BS, const float* __restrict__ Dc) {
    int g = blockIdx.x * 256 + threadIdx.x;
    int bh = g >> 12, ij = g & 4095, i = ij >> 6;
    float S = 0.f;
    size_t base = ((size_t)bh << 17) + ij;
    float bv = BS[base];
    float d  = Dc[(size_t)(bh * NC_) * 64 + i];
    for (int c = 0; c < NC_; ++c) {
        size_t idx = base + ((size_t)c << 12);
        float bv2 = 0.f, d2 = 0.f;
        if (c + 1 < NC_) {
            bv2 = BS[idx + 4096];
            d2  = Dc[(size_t)(bh * NC_ + c + 1) * 64 + i];
        }
        BS[idx] = S;
        S = d * S + bv;
        bv = bv2; d = d2;
    }
}

// ---------------------------------------------------------------------------
// Phase C fused with per-head LN + swish gate -> tiled bf16 A-layout.
// 512 threads (8 waves): 16 lanes per output row, 4 cols each.
__global__ __launch_bounds__(512) void scan_chunkC_ln(const float* __restrict__ rt,
                                                      const float* __restrict__ BS,
                                                      const float* __restrict__ oi,
                                                      const float* __restrict__ gb,
                                                      const float* __restrict__ lw,
                                                      const float* __restrict__ lb,
                                                      ushort* __restrict__ outt) {
    __shared__ float sS[64][64];
    __shared__ float sRt[CC_][68];
    int bid = blockIdx.x;
    int bh = bid >> 5, c = bid & (NC_ - 1);
    int b = bh >> 4, h = bh & 15;
    int tid = threadIdx.x;
    size_t sbase = ((size_t)bid) << 12;
    for (int q = tid; q < 1024; q += 512)
        *(float4*)&sS[q >> 4][(q & 15) << 2] = *(const float4*)&BS[sbase + (q << 2)];
    size_t base = ((size_t)(b * T_ + c * CC_)) * KD_ + h * 64;
    {
        int row = tid >> 4, col4 = (tid & 15) << 2;
        *(float4*)&sRt[row][col4] = *(const float4*)&rt[base + (size_t)row * KD_ + col4];
    }
    __syncthreads();
    int tau = tid >> 4, j0 = (tid & 15) * 4;
    size_t obase = base + (size_t)tau * KD_ + j0;
    float acc[4] __attribute__((aligned(16)));
    *(float4*)&acc[0] = *(const float4*)&oi[obase];
    for (int i = 0; i < 64; ++i) {
        float a = sRt[tau][i];
        float4 vv = *(const float4*)&sS[i][j0];
        acc[0] += a * vv.x; acc[1] += a * vv.y;
        acc[2] += a * vv.z; acc[3] += a * vv.w;
    }
    // layernorm over the 16-lane group (row of 64)
    float s = acc[0] + acc[1] + acc[2] + acc[3];
    s += __shfl_xor(s, 1, 64); s += __shfl_xor(s, 2, 64);
    s += __shfl_xor(s, 4, 64); s += __shfl_xor(s, 8, 64);
    float mean = s * (1.f / 64.f);
    float s2 = 0.f;
    #pragma unroll
    for (int q = 0; q < 4; ++q) { float dx = acc[q] - mean; s2 += dx * dx; }
    s2 += __shfl_xor(s2, 1, 64); s2 += __shfl_xor(s2, 2, 64);
    s2 += __shfl_xor(s2, 4, 64); s2 += __shfl_xor(s2, 8, 64);
    float inv = rsqrtf(s2 * (1.f / 64.f) + 1e-5f);
    float4 lwv = *(const float4*)&lw[j0];
    float4 lbv = *(const float4*)&lb[j0];
    float4 gv  = *(const float4*)&gb[obase];
    float lww[4] = {lwv.x, lwv.y, lwv.z, lwv.w};
    float lbb[4] = {lbv.x, lbv.y, lbv.z, lbv.w};
    float gvv[4] = {gv.x, gv.y, gv.z, gv.w};
    ushort o4[4];
    #pragma unroll
    for (int q = 0; q < 4; ++q) {
        float on = (acc[q] - mean) * inv * lww[q] + lbb[q];
        float g = gvv[q];
        o4[q] = bf16r(on * g / (1.f + expf(-g)));
    }
    int mrow = b * T_ + c * CC_ + tau;
    int col  = h * 64 + j0;
    int rb2 = mrow >> 7, kb2 = col >> 5, gg = (col >> 3) & 3;
    *(ushort4*)&outt[(((size_t)(rb2 * 32 + kb2)) << 12) + ((gg << 7) + (mrow & 127)) * 8 + (col & 7)] = *(ushort4*)o4;
}

// ---------------------------------------------------------------------------
extern "C" void kernel_launch(void* const* d_in, const int* in_sizes, int n_in,
                              void* d_out, int out_size, void* d_ws, size_t ws_size,
                              hipStream_t stream) {
    const float* x     = (const float*)d_in[0];
    const float* mu_x  = (const float*)d_in[1];
    const float* Wx1   = (const float*)d_in[2];
    const float* Wx2   = (const float*)d_in[3];
    const float* xbias = (const float*)d_in[4];
    const float* Wr    = (const float*)d_in[5];
    const float* Wk    = (const float*)d_in[6];
    const float* Wv    = (const float*)d_in[7];
    const float* Ww_a  = (const float*)d_in[8];
    const float* Ww_b  = (const float*)d_in[9];
    const float* bw    = (const float*)d_in[10];
    const float* Wg_a  = (const float*)d_in[11];
    const float* Wg_b  = (const float*)d_in[12];
    const float* bg    = (const float*)d_in[13];
    const float* bonus = (const float*)d_in[14];
    const float* ln_w  = (const float*)d_in[15];
    const float* ln_b  = (const float*)d_in[16];
    const float* Wo    = (const float*)d_in[17];
    float* out = (float*)d_out;

    // workspace layout (float units), with overlays (see launch order)
    float* ws   = (float*)d_ws;
    float* xm   = ws;                               // 4M floats: xmt_r|xmt_k; later gt
    float* lr   = xm   + (size_t)M_ * H_;           // lrt | wx2t (bf16 overlays)
    float* hidw = lr   + (size_t)M_ * 320;          // M_*64
    float* hidg = hidw + (size_t)M_ * 64;           // M_*64
    float* rb_  = hidg + (size_t)M_ * 64;           // M_*KD_ (rkv out z=0)
    float* kb_  = rb_  + (size_t)M_ * KD_;
    float* vb_  = kb_  + (size_t)M_ * KD_;
    float* db_  = vb_  + (size_t)M_ * KD_;
    float* gb_  = db_  + (size_t)M_ * KD_;          // first 1M floats double as part_g
    float* ob_  = gb_  + (size_t)M_ * KD_;
    float* BS   = ob_  + (size_t)M_ * KD_;          // 4M floats: part_w | xmt_v | scan B/S
    float* Dc   = BS   + (size_t)1024 * 4096;       // 1024*64
    float* wend = Dc + (size_t)1024 * 64;
    // bf16 overlays (ushort units)
    ushort* xmt_r = (ushort*)xm;                            // 8 MB
    ushort* xmt_k = (ushort*)(xm + (size_t)M_ * H_ / 2);    // 8 MB
    ushort* xmt_v = (ushort*)(BS + 1310720);                // 8 MB (past 4MB part_w)
    float*  partw = BS;                                     // 4 MB (step 3 only)
    float*  partg = gb_;                                    // 4 MB (step 3 only)
    ushort* gt    = (ushort*)xm;                            // 4 MB
    ushort* lrt   = (ushort*)lr;                            // 16*5*8192 = 655360 ush
    ushort* wx2t  = lrt + 655360;                           // 5*32*2*2048 = 655360 ush
    ushort* Wx1t  = (ushort*)wend;                          // 2048*320
    ushort* Wrt   = Wx1t + (size_t)H_ * 320;
    ushort* Wkt   = Wrt  + (size_t)H_ * KD_;
    ushort* Wvt   = Wkt  + (size_t)H_ * KD_;
    ushort* Wot   = Wvt  + (size_t)H_ * KD_;                // 1024*2048
    // DEDICATED (non-aliased) regions for musgemm's fp32 w/g outputs —
    // required because step 3 runs rkv (writes rb_/vb_) CONCURRENTLY with
    // split-K (reads xm_w/xm_g). R22's alias xm_w=rb_, xm_g=vb_ was a race.
    float*  xm_w  = (float*)(Wot + (size_t)KD_ * H_);       // 16 MB fp32
    float*  xm_g  = xm_w + (size_t)M_ * H_;                 // 16 MB fp32

    dim3 blk(256);

    // 0+1a. fused preprocessing: mix_mu + ALL weight conversions (one dispatch)
    prep_all<<<6624, blk, 0, stream>>>(x, mu_x, Wx1, Wr, Wk, Wv, Wo, Wx2,
                                       (ushort*)xm, Wx1t, Wrt, Wot, wx2t);

    // 1b. lrt = tanh((x + delta*mu_x) @ Wx1) as bf16 A-tiled per branch [MFMA, BK=64]
    gemm_bf16t_lr<<<dim3(5, M_ / 128), blk, 0, stream>>>((ushort*)xm, Wx1t, lrt);

    // 2. MFMA mus-GEMM + lerp (K=64, branch on z; 2560 blocks)
    musgemm_mfma<<<dim3(H_ / 64, M_ / 128, 5), blk, 0, stream>>>(lrt, wx2t, x, xbias,
                                                                 xmt_r, xm_w, xmt_k, xmt_v, xm_g);

    // 3. MERGED: r/k/v MFMA GEMM (768 blocks) + LoRA split-K (512 blocks) —
    //    both depend only on step 2; split-K fills slots while r/k/v drains.
    gemm_rkv_splitk<<<1280, blk, 0, stream>>>(xmt_r, xmt_k, xmt_v, Wrt, rb_,
                                              xm_w, xm_g, Ww_a, Wg_a, partw, partg);

    // 4. tanh reduce (z=2), then LoRA up-projections (z=2)
    reduce_tanh2<<<dim3(128, 2), blk, 0, stream>>>(partw, partg, hidw, hidg);
    gemm_f32_up2<<<dim3(KD_ / 64, M_ / 64, 2), blk, 0, stream>>>(hidw, hidg, Ww_b, Wg_b,
                                                                 bw, bg, db_, gb_);

    // 5. chunk-parallel scan; phases A and C at 512 threads (8 waves, 2x TLP)
    scan_chunkA<<<B_ * NH_ * NC_, dim3(512), 0, stream>>>(rb_, kb_, vb_, db_, bonus,
                                                          rb_ /*rt in place*/, ob_, BS, Dc);
    scan_chunkB<<<(B_ * NH_ * 4096) / 256, blk, 0, stream>>>(BS, Dc);
    scan_chunkC_ln<<<B_ * NH_ * NC_, dim3(512), 0, stream>>>(rb_, BS, ob_, gb_, ln_w, ln_b, gt);

    // 6. out = gated @ Wo  [bf16 MFMA, BK=64], 512 blocks, XCD-swizzled
    gemm_bf16t<0><<<dim3(H_ / 64, M_ / 128), blk, 0, stream>>>(gt, Wot, out, KD_, H_);
}